// Round 1
// baseline (790.608 us; speedup 1.0000x reference)
//
#include <hip/hip_runtime.h>

typedef unsigned short u16;
typedef __attribute__((ext_vector_type(8))) __bf16 bf16x8;
typedef __attribute__((ext_vector_type(4))) float f32x4;

#define NSEQ 2048
#define NDIM 1024
#define NHEAD 16
#define NTOK 4096
#define NX   4194304   /* NTOK*NDIM */
#define NWEL 1048576   /* NDIM*NDIM */

__device__ __forceinline__ u16 f2bf(float f) {
  unsigned u = __float_as_uint(f);
  return (u16)((u + 0x7fffu + ((u >> 16) & 1u)) >> 16);
}
__device__ __forceinline__ float bf2f(u16 h) {
  return __uint_as_float(((unsigned)h) << 16);
}
__device__ __forceinline__ bf16x8 ld16(const u16* p) {
  int4 v = *reinterpret_cast<const int4*>(p);
  return __builtin_bit_cast(bf16x8, v);
}
__device__ __forceinline__ f32x4 mfma16(bf16x8 a, bf16x8 b, f32x4 c) {
  return __builtin_amdgcn_mfma_f32_16x16x32_bf16(a, b, c, 0, 0, 0);
}

// ---------------- prep: split f32 -> bf16 hi/lo ----------------
__global__ __launch_bounds__(256) void k_prep(
    const float* __restrict__ x, const float* __restrict__ wq,
    const float* __restrict__ wk, const float* __restrict__ wv,
    const float* __restrict__ wo,
    u16* __restrict__ xh, u16* __restrict__ xl,
    u16* __restrict__ wh, u16* __restrict__ wl) {
  int g = blockIdx.x * 256 + threadIdx.x;  // 4-element groups
  const float4* src;
  u16 *dh, *dl;
  int idx;
  if (g < NX / 4) {
    src = (const float4*)x; dh = xh; dl = xl; idx = g;
  } else {
    int z = (g - NX / 4) / (NWEL / 4);
    int r = (g - NX / 4) % (NWEL / 4);
    src = (const float4*)(z == 0 ? wq : z == 1 ? wk : z == 2 ? wv : wo);
    dh = wh + (size_t)z * NWEL; dl = wl + (size_t)z * NWEL; idx = r;
  }
  float4 v = src[idx];
  u16 h0 = f2bf(v.x), h1 = f2bf(v.y), h2 = f2bf(v.z), h3 = f2bf(v.w);
  ushort4 hv = make_ushort4(h0, h1, h2, h3);
  ushort4 lv = make_ushort4(f2bf(v.x - bf2f(h0)), f2bf(v.y - bf2f(h1)),
                            f2bf(v.z - bf2f(h2)), f2bf(v.w - bf2f(h3)));
  ((ushort4*)dh)[idx] = hv;
  ((ushort4*)dl)[idx] = lv;
}

// ---------------- split-bf16 GEMM core: C = A * B^T (3 MFMA products) ----
// A: [M][1024] rows at t0..t0+127 (hi/lo), B: [N][1024] rows at j0..j0+127.
// 256 threads = 4 waves (2x2), each wave 64x64, acc[4][4] of 16x16 frags.
__device__ __forceinline__ void gemm_core(
    const u16* __restrict__ Ah, const u16* __restrict__ Al,
    const u16* __restrict__ Bh, const u16* __restrict__ Bl,
    int t0, int j0, u16* lds, f32x4 acc[4][4]) {
  const int tid = threadIdx.x;
  const int lane = tid & 63, wid = tid >> 6;
  const int wm = wid >> 1, wn = wid & 1;
  const int lr = lane & 15, lg = lane >> 4;
  u16* lah = lds;
  u16* lal = lds + 4096;
  u16* lbh = lds + 8192;
  u16* lbl = lds + 12288;
  for (int k0 = 0; k0 < NDIM; k0 += 32) {
    __syncthreads();
#pragma unroll
    for (int t = 0; t < 2; t++) {
      int c = tid + t * 256;  // 0..511 chunks of 8 u16
      int row = c >> 2, ch = c & 3;
      int4 va = *(const int4*)(Ah + (size_t)(t0 + row) * NDIM + k0 + ch * 8);
      int4 vb = *(const int4*)(Al + (size_t)(t0 + row) * NDIM + k0 + ch * 8);
      int4 vc = *(const int4*)(Bh + (size_t)(j0 + row) * NDIM + k0 + ch * 8);
      int4 vd = *(const int4*)(Bl + (size_t)(j0 + row) * NDIM + k0 + ch * 8);
      *(int4*)(lah + row * 32 + ch * 8) = va;
      *(int4*)(lal + row * 32 + ch * 8) = vb;
      *(int4*)(lbh + row * 32 + ch * 8) = vc;
      *(int4*)(lbl + row * 32 + ch * 8) = vd;
    }
    __syncthreads();
    bf16x8 afh[4], afl[4];
#pragma unroll
    for (int m = 0; m < 4; m++) {
      int off = (wm * 64 + m * 16 + lr) * 32 + lg * 8;
      afh[m] = ld16(lah + off);
      afl[m] = ld16(lal + off);
    }
#pragma unroll
    for (int n = 0; n < 4; n++) {
      int off = (wn * 64 + n * 16 + lr) * 32 + lg * 8;
      bf16x8 bfh = ld16(lbh + off);
      bf16x8 bfl = ld16(lbl + off);
#pragma unroll
      for (int m = 0; m < 4; m++) {
        acc[m][n] = mfma16(afh[m], bfh, acc[m][n]);
        acc[m][n] = mfma16(afh[m], bfl, acc[m][n]);
        acc[m][n] = mfma16(afl[m], bfh, acc[m][n]);
      }
    }
  }
}

// ---------------- QKV projection + RoPE epilogue ----------------
// z=0: Q (rope, split store), z=1: K (rope, split store), z=2: V (transposed bf16)
__global__ __launch_bounds__(256, 2) void k_qkv(
    const u16* __restrict__ xh, const u16* __restrict__ xl,
    const u16* __restrict__ wh, const u16* __restrict__ wl,
    const int* __restrict__ tokpos,
    u16* __restrict__ qh, u16* __restrict__ ql,
    u16* __restrict__ kh, u16* __restrict__ kl, u16* __restrict__ vt) {
  __shared__ __align__(16) u16 lds[16384];
  const int z = blockIdx.z;
  const int t0 = blockIdx.y * 128, j0 = blockIdx.x * 128;
  f32x4 acc[4][4];
#pragma unroll
  for (int m = 0; m < 4; m++)
#pragma unroll
    for (int n = 0; n < 4; n++) acc[m][n] = f32x4{0.f, 0.f, 0.f, 0.f};
  gemm_core(xh, xl, wh + (size_t)z * NWEL, wl + (size_t)z * NWEL, t0, j0, lds, acc);

  const int tid = threadIdx.x, lane = tid & 63, wid = tid >> 6;
  const int wm = wid >> 1, wn = wid & 1, lr = lane & 15, lg = lane >> 4;
  if (z < 2) {
    u16* dh = (z == 0) ? qh : kh;
    u16* dl = (z == 0) ? ql : kl;
    double invf_n[4];
#pragma unroll
    for (int n = 0; n < 4; n++) {
      int dk2 = ((j0 + wn * 64 + n * 16 + lr) & 63) & ~1;
      invf_n[n] = exp((double)dk2 * (-9.210340371976184 / 64.0));
    }
#pragma unroll
    for (int m = 0; m < 4; m++) {
#pragma unroll
      for (int r = 0; r < 4; r++) {
        int row = t0 + wm * 64 + m * 16 + lg * 4 + r;  // token index
        int pos = tokpos[row];
#pragma unroll
        for (int n = 0; n < 4; n++) {
          float val = acc[m][n][r];
          float nb = __shfl_xor(val, 1);
          int col = j0 + wn * 64 + n * 16 + lr;
          int dk = col & 63, h = col >> 6;
          double ang = (double)pos * invf_n[n];
          double kq = rint(ang * 0.15915494309189535);
          float a = (float)(ang - kq * 6.283185307179586);
          float sn = sinf(a), cs = cosf(a);
          float rv = (dk & 1) ? (nb * sn + val * cs) : (val * cs - nb * sn);
          int b = row >> 11, srow = row & 2047;
          size_t off = ((size_t)((b * NHEAD + h) * NSEQ + srow)) * 64 + dk;
          u16 hi = f2bf(rv);
          dh[off] = hi;
          dl[off] = f2bf(rv - bf2f(hi));
        }
      }
    }
  } else {
#pragma unroll
    for (int m = 0; m < 4; m++) {
#pragma unroll
      for (int r = 0; r < 4; r++) {
        int row = t0 + wm * 64 + m * 16 + lg * 4 + r;
        int b = row >> 11, srow = row & 2047;
#pragma unroll
        for (int n = 0; n < 4; n++) {
          int col = j0 + wn * 64 + n * 16 + lr;
          int dk = col & 63, h = col >> 6;
          vt[((size_t)((b * NHEAD + h) * 64 + dk)) * NSEQ + srow] = f2bf(acc[m][n][r]);
        }
      }
    }
  }
}

// ---------------- causal flash attention ----------------
// grid (32 qblocks, 32 bh). 4 waves, each owns 16 q rows. KV tiles of 64.
__global__ __launch_bounds__(256, 2) void k_attn(
    const u16* __restrict__ qh, const u16* __restrict__ ql,
    const u16* __restrict__ kh, const u16* __restrict__ kl,
    const u16* __restrict__ vt,
    u16* __restrict__ ah, u16* __restrict__ al) {
  __shared__ __align__(16) u16 skh[4096];
  __shared__ __align__(16) u16 skl[4096];
  __shared__ __align__(16) u16 svt[4096];
  __shared__ __align__(16) u16 sp[4096];
  const int tid = threadIdx.x, lane = tid & 63, w = tid >> 6;
  const int lr = lane & 15, lg = lane >> 4;
  const int qblk = 31 - blockIdx.x;  // heavy blocks dispatch first
  const int bh = blockIdx.y;
  const int q0 = qblk * 64;
  const size_t base = (size_t)bh * NSEQ * 64;   // q/k: [bh][s][dk]
  const size_t vbase = (size_t)bh * 64 * NSEQ;  // vt:  [bh][dk][s]

  bf16x8 qfh[2], qfl[2];
  const int qrow = q0 + w * 16 + lr;
#pragma unroll
  for (int kk = 0; kk < 2; kk++) {
    qfh[kk] = ld16(qh + base + (size_t)qrow * 64 + kk * 32 + lg * 8);
    qfl[kk] = ld16(ql + base + (size_t)qrow * 64 + kk * 32 + lg * 8);
  }
  float mrun[4], lrun[4];
  f32x4 oacc[4];
#pragma unroll
  for (int r = 0; r < 4; r++) { mrun[r] = -__builtin_inff(); lrun[r] = 0.f; }
#pragma unroll
  for (int nf = 0; nf < 4; nf++) oacc[nf] = f32x4{0.f, 0.f, 0.f, 0.f};

  for (int kt = 0; kt <= qblk; kt++) {
    __syncthreads();
#pragma unroll
    for (int t = 0; t < 2; t++) {
      int c = tid + t * 256;  // 0..511
      int row = c >> 3, co = (c & 7) * 8;
      int sco = co ^ ((row & 7) * 8);  // XOR swizzle (8-elem blocks)
      *(int4*)(skh + row * 64 + sco) =
          *(const int4*)(kh + base + (size_t)(kt * 64 + row) * 64 + co);
      *(int4*)(skl + row * 64 + sco) =
          *(const int4*)(kl + base + (size_t)(kt * 64 + row) * 64 + co);
      *(int4*)(svt + row * 64 + sco) =
          *(const int4*)(vt + vbase + (size_t)row * NSEQ + kt * 64 + co);
    }
    __syncthreads();
    // QK^T (split: hh + hl + lh)
    f32x4 sacc[4];
#pragma unroll
    for (int nf = 0; nf < 4; nf++) sacc[nf] = f32x4{0.f, 0.f, 0.f, 0.f};
#pragma unroll
    for (int nf = 0; nf < 4; nf++) {
      int krow = nf * 16 + lr;
#pragma unroll
      for (int kk = 0; kk < 2; kk++) {
        int off = krow * 64 + ((kk * 32 + lg * 8) ^ ((krow & 7) * 8));
        bf16x8 bh_ = ld16(skh + off);
        bf16x8 bl_ = ld16(skl + off);
        sacc[nf] = mfma16(qfh[kk], bh_, sacc[nf]);
        sacc[nf] = mfma16(qfh[kk], bl_, sacc[nf]);
        sacc[nf] = mfma16(qfl[kk], bh_, sacc[nf]);
      }
    }
    // scale + causal mask + online softmax
    float alpha[4];
#pragma unroll
    for (int r = 0; r < 4; r++) {
      int row = q0 + w * 16 + lg * 4 + r;
      float sv[4];
      float smax = -__builtin_inff();
#pragma unroll
      for (int nf = 0; nf < 4; nf++) {
        int colg = kt * 64 + nf * 16 + lr;
        float s = sacc[nf][r] * 0.125f;
        if (colg > row) s = -__builtin_inff();
        sv[nf] = s;
        smax = fmaxf(smax, s);
      }
#pragma unroll
      for (int o = 1; o < 16; o <<= 1) smax = fmaxf(smax, __shfl_xor(smax, o));
      float mnew = fmaxf(mrun[r], smax);
      float al_ = __expf(mrun[r] - mnew);
      float rsum = 0.f;
      int prow = w * 16 + lg * 4 + r;
#pragma unroll
      for (int nf = 0; nf < 4; nf++) {
        float p = __expf(sv[nf] - mnew);
        rsum += p;
        int pcol = nf * 16 + lr;
        sp[prow * 64 + (pcol ^ ((prow & 7) * 8))] = f2bf(p);
      }
#pragma unroll
      for (int o = 1; o < 16; o <<= 1) rsum += __shfl_xor(rsum, o);
      lrun[r] = lrun[r] * al_ + rsum;
      mrun[r] = mnew;
      alpha[r] = al_;
    }
#pragma unroll
    for (int nf = 0; nf < 4; nf++)
#pragma unroll
      for (int r = 0; r < 4; r++) oacc[nf][r] *= alpha[r];
    __syncthreads();  // order P writes before reads; all intra-wave rows
    // P * V  (plain bf16)
#pragma unroll
    for (int kk = 0; kk < 2; kk++) {
      int prow = w * 16 + lr;
      bf16x8 pa = ld16(sp + prow * 64 + ((kk * 32 + lg * 8) ^ ((prow & 7) * 8)));
#pragma unroll
      for (int nf = 0; nf < 4; nf++) {
        int vrow = nf * 16 + lr;
        bf16x8 vb = ld16(svt + vrow * 64 + ((kk * 32 + lg * 8) ^ ((vrow & 7) * 8)));
        oacc[nf] = mfma16(pa, vb, oacc[nf]);
      }
    }
  }
  // epilogue: normalize, split-store to attn-out [token][1024]
  const int b = bh >> 4, h = bh & 15;
#pragma unroll
  for (int r = 0; r < 4; r++) {
    float inv = 1.0f / lrun[r];
    int row = q0 + w * 16 + lg * 4 + r;  // s
    size_t toff = ((size_t)(b * NSEQ + row)) * NDIM + h * 64;
#pragma unroll
    for (int nf = 0; nf < 4; nf++) {
      float val = oacc[nf][r] * inv;
      u16 hi = f2bf(val);
      ah[toff + nf * 16 + lr] = hi;
      al[toff + nf * 16 + lr] = f2bf(val - bf2f(hi));
    }
  }
}

// ---------------- final projection: out = A * Wo^T (f32 store) ----------
__global__ __launch_bounds__(256, 2) void k_out(
    const u16* __restrict__ ah, const u16* __restrict__ al,
    const u16* __restrict__ wh, const u16* __restrict__ wl,
    float* __restrict__ out) {
  __shared__ __align__(16) u16 lds[16384];
  const int t0 = blockIdx.y * 128, j0 = blockIdx.x * 128;
  f32x4 acc[4][4];
#pragma unroll
  for (int m = 0; m < 4; m++)
#pragma unroll
    for (int n = 0; n < 4; n++) acc[m][n] = f32x4{0.f, 0.f, 0.f, 0.f};
  gemm_core(ah, al, wh, wl, t0, j0, lds, acc);
  const int tid = threadIdx.x, lane = tid & 63, wid = tid >> 6;
  const int wm = wid >> 1, wn = wid & 1, lr = lane & 15, lg = lane >> 4;
#pragma unroll
  for (int m = 0; m < 4; m++)
#pragma unroll
    for (int r = 0; r < 4; r++) {
      int row = t0 + wm * 64 + m * 16 + lg * 4 + r;
#pragma unroll
      for (int n = 0; n < 4; n++) {
        int col = j0 + wn * 64 + n * 16 + lr;
        out[(size_t)row * NDIM + col] = acc[m][n][r];
      }
    }
}

extern "C" void kernel_launch(void* const* d_in, const int* in_sizes, int n_in,
                              void* d_out, int out_size, void* d_ws, size_t ws_size,
                              hipStream_t stream) {
  (void)in_sizes; (void)n_in; (void)out_size; (void)ws_size;
  const float* x = (const float*)d_in[0];
  const int* tokpos = (const int*)d_in[1];
  const float* wq = (const float*)d_in[2];
  const float* wk = (const float*)d_in[3];
  const float* wv = (const float*)d_in[4];
  const float* wo = (const float*)d_in[5];
  float* out = (float*)d_out;

  u16* ws = (u16*)d_ws;
  u16* xh = ws;              // NX  (reused as attn-out hi after projections)
  u16* xl = xh + NX;         // NX  (reused as attn-out lo)
  u16* wh = xl + NX;         // 4*NWEL (q,k,v,o)
  u16* wl = wh + 4 * (size_t)NWEL;
  u16* qh = wl + 4 * (size_t)NWEL;
  u16* ql = qh + NX;
  u16* kh = ql + NX;
  u16* kl = kh + NX;
  u16* vt = kl + NX;         // total 75.5 MB

  k_prep<<<dim3(8192), dim3(256), 0, stream>>>(x, wq, wk, wv, wo, xh, xl, wh, wl);
  k_qkv<<<dim3(8, 32, 3), dim3(256), 0, stream>>>(xh, xl, wh, wl, tokpos,
                                                  qh, ql, kh, kl, vt);
  k_attn<<<dim3(32, 32), dim3(256), 0, stream>>>(qh, ql, kh, kl, vt, xh, xl);
  k_out<<<dim3(8, 32), dim3(256), 0, stream>>>(xh, xl, wh + 3 * (size_t)NWEL,
                                               wl + 3 * (size_t)NWEL, out);
}

// Round 2
// 768.917 us; speedup vs baseline: 1.0282x; 1.0282x over previous
//
#include <hip/hip_runtime.h>

typedef unsigned short u16;
typedef __attribute__((ext_vector_type(8))) __bf16 bf16x8;
typedef __attribute__((ext_vector_type(4))) float f32x4;

#define NSEQ 2048
#define NDIM 1024
#define NHEAD 16
#define NTOK 4096
#define NX   4194304   /* NTOK*NDIM */
#define NWEL 1048576   /* NDIM*NDIM */

__device__ __forceinline__ u16 f2bf(float f) {
  unsigned u = __float_as_uint(f);
  return (u16)((u + 0x7fffu + ((u >> 16) & 1u)) >> 16);
}
__device__ __forceinline__ float bf2f(u16 h) {
  return __uint_as_float(((unsigned)h) << 16);
}
__device__ __forceinline__ bf16x8 ld16(const u16* p) {
  int4 v = *reinterpret_cast<const int4*>(p);
  return __builtin_bit_cast(bf16x8, v);
}
__device__ __forceinline__ f32x4 mfma16(bf16x8 a, bf16x8 b, f32x4 c) {
  return __builtin_amdgcn_mfma_f32_16x16x32_bf16(a, b, c, 0, 0, 0);
}
// async global->LDS, 16B per lane; LDS dest = wave-uniform base + lane*16
__device__ __forceinline__ void gload16(const u16* g, u16* l) {
  __builtin_amdgcn_global_load_lds(
      (const __attribute__((address_space(1))) void*)g,
      (__attribute__((address_space(3))) void*)l, 16, 0, 0);
}

// ---------------- prep: split f32 -> bf16 hi/lo ----------------
__global__ __launch_bounds__(256) void k_prep(
    const float* __restrict__ x, const float* __restrict__ wq,
    const float* __restrict__ wk, const float* __restrict__ wv,
    const float* __restrict__ wo,
    u16* __restrict__ xh, u16* __restrict__ xl,
    u16* __restrict__ wh, u16* __restrict__ wl) {
  int g = blockIdx.x * 256 + threadIdx.x;  // 4-element groups
  const float4* src;
  u16 *dh, *dl;
  int idx;
  if (g < NX / 4) {
    src = (const float4*)x; dh = xh; dl = xl; idx = g;
  } else {
    int z = (g - NX / 4) / (NWEL / 4);
    int r = (g - NX / 4) % (NWEL / 4);
    src = (const float4*)(z == 0 ? wq : z == 1 ? wk : z == 2 ? wv : wo);
    dh = wh + (size_t)z * NWEL; dl = wl + (size_t)z * NWEL; idx = r;
  }
  float4 v = src[idx];
  u16 h0 = f2bf(v.x), h1 = f2bf(v.y), h2 = f2bf(v.z), h3 = f2bf(v.w);
  ushort4 hv = make_ushort4(h0, h1, h2, h3);
  ushort4 lv = make_ushort4(f2bf(v.x - bf2f(h0)), f2bf(v.y - bf2f(h1)),
                            f2bf(v.z - bf2f(h2)), f2bf(v.w - bf2f(h3)));
  ((ushort4*)dh)[idx] = hv;
  ((ushort4*)dl)[idx] = lv;
}

// ---------------- split-bf16 GEMM core: C = A * B^T ----------------
// NPROD=3: hh+hl+lh (split).  NPROD=1: hh only (plain bf16).
// A rows t0..t0+127, B rows j0..j0+127, K=1024, BK=32.
// 256 threads = 4 waves (2x2), each wave 64x64 out, acc[4][4] 16x16 frags.
// LDS staging layout: [row][32] u16, linear in tid*8 -> global_load_lds ok.
template <int NPROD>
__device__ __forceinline__ void gemm_core(
    const u16* __restrict__ Ah, const u16* __restrict__ Al,
    const u16* __restrict__ Bh, const u16* __restrict__ Bl,
    int t0, int j0, u16* lds, f32x4 acc[4][4]) {
  const int tid = threadIdx.x;
  const int lane = tid & 63, wid = tid >> 6;
  const int wm = wid >> 1, wn = wid & 1;
  const int lr = lane & 15, lg = lane >> 4;
  u16* lah = lds;
  u16* lbh = lds + 4096;
  u16* lal = lds + 8192;
  u16* lbl = lds + 12288;
  const int row = tid >> 2, ch = (tid & 3) * 8;  // issue 0; issue 1 adds 64 rows
  for (int k0 = 0; k0 < NDIM; k0 += 32) {
    __syncthreads();
    gload16(Ah + (size_t)(t0 + row) * NDIM + k0 + ch, lah + tid * 8);
    gload16(Ah + (size_t)(t0 + 64 + row) * NDIM + k0 + ch, lah + 2048 + tid * 8);
    gload16(Bh + (size_t)(j0 + row) * NDIM + k0 + ch, lbh + tid * 8);
    gload16(Bh + (size_t)(j0 + 64 + row) * NDIM + k0 + ch, lbh + 2048 + tid * 8);
    if constexpr (NPROD == 3) {
      gload16(Al + (size_t)(t0 + row) * NDIM + k0 + ch, lal + tid * 8);
      gload16(Al + (size_t)(t0 + 64 + row) * NDIM + k0 + ch, lal + 2048 + tid * 8);
      gload16(Bl + (size_t)(j0 + row) * NDIM + k0 + ch, lbl + tid * 8);
      gload16(Bl + (size_t)(j0 + 64 + row) * NDIM + k0 + ch, lbl + 2048 + tid * 8);
    }
    __syncthreads();
    bf16x8 afh[4], afl[4];
#pragma unroll
    for (int m = 0; m < 4; m++) {
      int off = (wm * 64 + m * 16 + lr) * 32 + lg * 8;
      afh[m] = ld16(lah + off);
      if constexpr (NPROD == 3) afl[m] = ld16(lal + off);
    }
#pragma unroll
    for (int n = 0; n < 4; n++) {
      int off = (wn * 64 + n * 16 + lr) * 32 + lg * 8;
      bf16x8 bfh = ld16(lbh + off);
      bf16x8 bfl;
      if constexpr (NPROD == 3) bfl = ld16(lbl + off);
#pragma unroll
      for (int m = 0; m < 4; m++) {
        acc[m][n] = mfma16(afh[m], bfh, acc[m][n]);
        if constexpr (NPROD == 3) {
          acc[m][n] = mfma16(afh[m], bfl, acc[m][n]);
          acc[m][n] = mfma16(afl[m], bfh, acc[m][n]);
        }
      }
    }
  }
}

// ---------------- QKV projection + RoPE epilogue ----------------
// z=0: Q (rope, split store), z=1: K (rope, split store), z=2: V (transposed)
__global__ __launch_bounds__(256, 2) void k_qkv(
    const u16* __restrict__ xh, const u16* __restrict__ xl,
    const u16* __restrict__ wh, const u16* __restrict__ wl,
    const int* __restrict__ tokpos,
    u16* __restrict__ qh, u16* __restrict__ ql,
    u16* __restrict__ kh, u16* __restrict__ kl, u16* __restrict__ vt) {
  __shared__ __align__(16) u16 lds[16384];
  const int z = blockIdx.z;
  const int t0 = blockIdx.y * 128, j0 = blockIdx.x * 128;
  const int h0 = j0 >> 6;  // first head covered by this col-tile (2 heads/tile)
  f32x4 acc[4][4];
#pragma unroll
  for (int m = 0; m < 4; m++)
#pragma unroll
    for (int n = 0; n < 4; n++) acc[m][n] = f32x4{0.f, 0.f, 0.f, 0.f};
  if (z < 2)
    gemm_core<3>(xh, xl, wh + (size_t)z * NWEL, wl + (size_t)z * NWEL, t0, j0, lds, acc);
  else
    gemm_core<1>(xh, xl, wh + (size_t)z * NWEL, wl + (size_t)z * NWEL, t0, j0, lds, acc);

  const int tid = threadIdx.x, lane = tid & 63, wid = tid >> 6;
  const int wm = wid >> 1, wn = wid & 1, lr = lane & 15, lg = lane >> 4;
  const int b = t0 >> 11, s0 = t0 & 2047;

  if (z < 2) {
    u16* dh = (z == 0) ? qh : kh;
    u16* dl = (z == 0) ? ql : kl;
    // ---- RoPE into registers ----
    float rv[4][4][4];
    double invf_n[4];
#pragma unroll
    for (int n = 0; n < 4; n++) {
      int dk2 = ((j0 + wn * 64 + n * 16 + lr) & 63) & ~1;
      invf_n[n] = exp((double)dk2 * (-9.210340371976184 / 64.0));
    }
#pragma unroll
    for (int m = 0; m < 4; m++) {
#pragma unroll
      for (int r = 0; r < 4; r++) {
        int pos = tokpos[t0 + wm * 64 + m * 16 + lg * 4 + r];
#pragma unroll
        for (int n = 0; n < 4; n++) {
          float val = acc[m][n][r];
          float nb = __shfl_xor(val, 1);
          int dk = (j0 + wn * 64 + n * 16 + lr) & 63;
          double ang = (double)pos * invf_n[n];
          double kq = rint(ang * 0.15915494309189535);
          float a = (float)(ang - kq * 6.283185307179586);
          float sn = sinf(a), cs = cosf(a);
          rv[m][r][n] = (dk & 1) ? (nb * sn + val * cs) : (val * cs - nb * sn);
        }
      }
    }
    // ---- two staged passes (hi, then lo) through LDS, coalesced out ----
#pragma unroll
    for (int pass = 0; pass < 2; pass++) {
      __syncthreads();
#pragma unroll
      for (int m = 0; m < 4; m++)
#pragma unroll
        for (int r = 0; r < 4; r++) {
          int rloc = wm * 64 + m * 16 + lg * 4 + r;
#pragma unroll
          for (int n = 0; n < 4; n++) {
            int cloc = wn * 64 + n * 16 + lr;
            float v = rv[m][r][n];
            u16 hi = f2bf(v);
            lds[rloc * 128 + cloc] = pass == 0 ? hi : f2bf(v - bf2f(hi));
          }
        }
      __syncthreads();
      u16* dst = pass == 0 ? dh : dl;
#pragma unroll
      for (int i = 0; i < 8; i++) {
        int idx = tid + i * 256;     // 0..2047 chunks of 8 u16
        int r = idx >> 4, cc = idx & 15;
        int4 v = *(int4*)(lds + r * 128 + cc * 8);
        int h2 = cc >> 3, dk = (cc & 7) * 8;
        size_t off = ((size_t)((b * NHEAD + h0 + h2) * NSEQ + s0 + r)) * 64 + dk;
        *(int4*)(dst + off) = v;
      }
    }
  } else {
    // ---- V: transpose in LDS (swizzled), coalesced out to vt[bh][dk][s] ----
    __syncthreads();
#pragma unroll
    for (int m = 0; m < 4; m++)
#pragma unroll
      for (int r = 0; r < 4; r++) {
        int rloc = wm * 64 + m * 16 + lg * 4 + r;
#pragma unroll
        for (int n = 0; n < 4; n++) {
          int cloc = wn * 64 + n * 16 + lr;
          lds[cloc * 128 + (rloc ^ ((cloc & 15) << 3))] = f2bf(acc[m][n][r]);
        }
      }
    __syncthreads();
#pragma unroll
    for (int i = 0; i < 8; i++) {
      int idx = tid + i * 256;
      int col = idx >> 4, rc = idx & 15;
      int4 v = *(int4*)(lds + col * 128 + ((rc * 8) ^ ((col & 15) << 3)));
      int h2 = col >> 6, dk = col & 63;
      size_t off = ((size_t)((b * NHEAD + h0 + h2) * 64 + dk)) * NSEQ + s0 + rc * 8;
      *(int4*)(vt + off) = v;
    }
  }
}

// ---------------- causal flash attention ----------------
// grid (32 qblocks, 32 bh). 4 waves, each owns 16 q rows. KV tiles of 64.
__global__ __launch_bounds__(256, 2) void k_attn(
    const u16* __restrict__ qh, const u16* __restrict__ ql,
    const u16* __restrict__ kh, const u16* __restrict__ kl,
    const u16* __restrict__ vt,
    u16* __restrict__ ah, u16* __restrict__ al) {
  __shared__ __align__(16) u16 skh[4096];
  __shared__ __align__(16) u16 skl[4096];
  __shared__ __align__(16) u16 svt[4096];
  __shared__ __align__(16) u16 sp[4096];
  const int tid = threadIdx.x, lane = tid & 63, w = tid >> 6;
  const int lr = lane & 15, lg = lane >> 4;
  const int qblk = 31 - blockIdx.x;  // heavy blocks dispatch first
  const int bh = blockIdx.y;
  const int q0 = qblk * 64;
  const size_t base = (size_t)bh * NSEQ * 64;   // q/k: [bh][s][dk]
  const size_t vbase = (size_t)bh * 64 * NSEQ;  // vt:  [bh][dk][s]

  bf16x8 qfh[2], qfl[2];
  const int qrow = q0 + w * 16 + lr;
#pragma unroll
  for (int kk = 0; kk < 2; kk++) {
    qfh[kk] = ld16(qh + base + (size_t)qrow * 64 + kk * 32 + lg * 8);
    qfl[kk] = ld16(ql + base + (size_t)qrow * 64 + kk * 32 + lg * 8);
  }
  float mrun[4], lrun[4];
  f32x4 oacc[4];
#pragma unroll
  for (int r = 0; r < 4; r++) { mrun[r] = -__builtin_inff(); lrun[r] = 0.f; }
#pragma unroll
  for (int nf = 0; nf < 4; nf++) oacc[nf] = f32x4{0.f, 0.f, 0.f, 0.f};

  for (int kt = 0; kt <= qblk; kt++) {
    __syncthreads();
#pragma unroll
    for (int t = 0; t < 2; t++) {
      int c = tid + t * 256;  // 0..511
      int row = c >> 3, co = (c & 7) * 8;
      int sco = co ^ ((row & 7) * 8);  // XOR swizzle (8-elem blocks)
      *(int4*)(skh + row * 64 + sco) =
          *(const int4*)(kh + base + (size_t)(kt * 64 + row) * 64 + co);
      *(int4*)(skl + row * 64 + sco) =
          *(const int4*)(kl + base + (size_t)(kt * 64 + row) * 64 + co);
      *(int4*)(svt + row * 64 + sco) =
          *(const int4*)(vt + vbase + (size_t)row * NSEQ + kt * 64 + co);
    }
    __syncthreads();
    // QK^T (split: hh + hl + lh)
    f32x4 sacc[4];
#pragma unroll
    for (int nf = 0; nf < 4; nf++) sacc[nf] = f32x4{0.f, 0.f, 0.f, 0.f};
#pragma unroll
    for (int nf = 0; nf < 4; nf++) {
      int krow = nf * 16 + lr;
#pragma unroll
      for (int kk = 0; kk < 2; kk++) {
        int off = krow * 64 + ((kk * 32 + lg * 8) ^ ((krow & 7) * 8));
        bf16x8 bh_ = ld16(skh + off);
        bf16x8 bl_ = ld16(skl + off);
        sacc[nf] = mfma16(qfh[kk], bh_, sacc[nf]);
        sacc[nf] = mfma16(qfh[kk], bl_, sacc[nf]);
        sacc[nf] = mfma16(qfl[kk], bh_, sacc[nf]);
      }
    }
    // scale + causal mask + online softmax
    float alpha[4];
#pragma unroll
    for (int r = 0; r < 4; r++) {
      int row = q0 + w * 16 + lg * 4 + r;
      float sv[4];
      float smax = -__builtin_inff();
#pragma unroll
      for (int nf = 0; nf < 4; nf++) {
        int colg = kt * 64 + nf * 16 + lr;
        float s = sacc[nf][r] * 0.125f;
        if (colg > row) s = -__builtin_inff();
        sv[nf] = s;
        smax = fmaxf(smax, s);
      }
#pragma unroll
      for (int o = 1; o < 16; o <<= 1) smax = fmaxf(smax, __shfl_xor(smax, o));
      float mnew = fmaxf(mrun[r], smax);
      float al_ = __expf(mrun[r] - mnew);
      float rsum = 0.f;
      int prow = w * 16 + lg * 4 + r;
#pragma unroll
      for (int nf = 0; nf < 4; nf++) {
        float p = __expf(sv[nf] - mnew);
        rsum += p;
        int pcol = nf * 16 + lr;
        sp[prow * 64 + (pcol ^ ((prow & 7) * 8))] = f2bf(p);
      }
#pragma unroll
      for (int o = 1; o < 16; o <<= 1) rsum += __shfl_xor(rsum, o);
      lrun[r] = lrun[r] * al_ + rsum;
      mrun[r] = mnew;
      alpha[r] = al_;
    }
#pragma unroll
    for (int nf = 0; nf < 4; nf++)
#pragma unroll
      for (int r = 0; r < 4; r++) oacc[nf][r] *= alpha[r];
    __syncthreads();  // order P writes before reads; all intra-wave rows
    // P * V  (plain bf16)
#pragma unroll
    for (int kk = 0; kk < 2; kk++) {
      int prow = w * 16 + lr;
      bf16x8 pa = ld16(sp + prow * 64 + ((kk * 32 + lg * 8) ^ ((prow & 7) * 8)));
#pragma unroll
      for (int nf = 0; nf < 4; nf++) {
        int vrow = nf * 16 + lr;
        bf16x8 vb = ld16(svt + vrow * 64 + ((kk * 32 + lg * 8) ^ ((vrow & 7) * 8)));
        oacc[nf] = mfma16(pa, vb, oacc[nf]);
      }
    }
  }
  // epilogue: normalize, split-store to attn-out [token][1024]
  const int b = bh >> 4, h = bh & 15;
#pragma unroll
  for (int r = 0; r < 4; r++) {
    float inv = 1.0f / lrun[r];
    int row = q0 + w * 16 + lg * 4 + r;  // s
    size_t toff = ((size_t)(b * NSEQ + row)) * NDIM + h * 64;
#pragma unroll
    for (int nf = 0; nf < 4; nf++) {
      float val = oacc[nf][r] * inv;
      u16 hi = f2bf(val);
      ah[toff + nf * 16 + lr] = hi;
      al[toff + nf * 16 + lr] = f2bf(val - bf2f(hi));
    }
  }
}

// ---------------- final projection: out = A * Wo^T (f32 store) ----------
__global__ __launch_bounds__(256, 2) void k_out(
    const u16* __restrict__ ah, const u16* __restrict__ al,
    const u16* __restrict__ wh, const u16* __restrict__ wl,
    float* __restrict__ out) {
  __shared__ __align__(16) u16 lds[16384];
  const int t0 = blockIdx.y * 128, j0 = blockIdx.x * 128;
  f32x4 acc[4][4];
#pragma unroll
  for (int m = 0; m < 4; m++)
#pragma unroll
    for (int n = 0; n < 4; n++) acc[m][n] = f32x4{0.f, 0.f, 0.f, 0.f};
  gemm_core<3>(ah, al, wh, wl, t0, j0, lds, acc);
  const int tid = threadIdx.x, lane = tid & 63, wid = tid >> 6;
  const int wm = wid >> 1, wn = wid & 1, lr = lane & 15, lg = lane >> 4;
#pragma unroll
  for (int m = 0; m < 4; m++)
#pragma unroll
    for (int r = 0; r < 4; r++) {
      int row = t0 + wm * 64 + m * 16 + lg * 4 + r;
#pragma unroll
      for (int n = 0; n < 4; n++) {
        int col = j0 + wn * 64 + n * 16 + lr;
        out[(size_t)row * NDIM + col] = acc[m][n][r];
      }
    }
}

extern "C" void kernel_launch(void* const* d_in, const int* in_sizes, int n_in,
                              void* d_out, int out_size, void* d_ws, size_t ws_size,
                              hipStream_t stream) {
  (void)in_sizes; (void)n_in; (void)out_size; (void)ws_size;
  const float* x = (const float*)d_in[0];
  const int* tokpos = (const int*)d_in[1];
  const float* wq = (const float*)d_in[2];
  const float* wk = (const float*)d_in[3];
  const float* wv = (const float*)d_in[4];
  const float* wo = (const float*)d_in[5];
  float* out = (float*)d_out;

  u16* ws = (u16*)d_ws;
  u16* xh = ws;              // NX  (reused as attn-out hi after projections)
  u16* xl = xh + NX;         // NX  (reused as attn-out lo)
  u16* wh = xl + NX;         // 4*NWEL (q,k,v,o)
  u16* wl = wh + 4 * (size_t)NWEL;
  u16* qh = wl + 4 * (size_t)NWEL;
  u16* ql = qh + NX;
  u16* kh = ql + NX;
  u16* kl = kh + NX;
  u16* vt = kl + NX;         // total 75.5 MB

  k_prep<<<dim3(8192), dim3(256), 0, stream>>>(x, wq, wk, wv, wo, xh, xl, wh, wl);
  k_qkv<<<dim3(8, 32, 3), dim3(256), 0, stream>>>(xh, xl, wh, wl, tokpos,
                                                  qh, ql, kh, kl, vt);
  k_attn<<<dim3(32, 32), dim3(256), 0, stream>>>(qh, ql, kh, kl, vt, xh, xl);
  k_out<<<dim3(8, 32), dim3(256), 0, stream>>>(xh, xl, wh + 3 * (size_t)NWEL,
                                               wl + 3 * (size_t)NWEL, out);
}

// Round 3
// 293.778 us; speedup vs baseline: 2.6912x; 2.6173x over previous
//
#include <hip/hip_runtime.h>

typedef unsigned short u16;
typedef __attribute__((ext_vector_type(8))) __bf16 bf16x8;
typedef __attribute__((ext_vector_type(4))) float f32x4;

#define NSEQ 2048
#define NDIM 1024
#define NHEAD 16
#define NTOK 4096
#define NX   4194304   /* NTOK*NDIM */
#define NWEL 1048576   /* NDIM*NDIM */

__device__ __forceinline__ u16 f2bf(float f) {
  unsigned u = __float_as_uint(f);
  return (u16)((u + 0x7fffu + ((u >> 16) & 1u)) >> 16);
}
__device__ __forceinline__ float bf2f(u16 h) {
  return __uint_as_float(((unsigned)h) << 16);
}
__device__ __forceinline__ bf16x8 ld16(const u16* p) {
  int4 v = *reinterpret_cast<const int4*>(p);
  return __builtin_bit_cast(bf16x8, v);
}
__device__ __forceinline__ f32x4 mfma16(bf16x8 a, bf16x8 b, f32x4 c) {
  return __builtin_amdgcn_mfma_f32_16x16x32_bf16(a, b, c, 0, 0, 0);
}
// async global->LDS, 16B per lane; LDS dest = wave-uniform base + lane*16
__device__ __forceinline__ void gload16(const u16* g, u16* l) {
  __builtin_amdgcn_global_load_lds(
      (const __attribute__((address_space(1))) void*)g,
      (__attribute__((address_space(3))) void*)l, 16, 0, 0);
}

// GEMM k-loop as a macro: NO function boundary around the accumulator array
// (round-2 post-mortem: acc passed as pointer param -> SROA failure -> acc in
// scratch -> 1.7 GB of spill writes per dispatch, VGPR_Count=60).
// Requires in scope: lds/lah/lbh/lal/lbl, tid, wm, wn, lr, lg, f32x4 acc[4][4].
// A/B panels: 128 rows x 1024 cols (hi+lo), BK=32, 3 MFMA products (hh+hl+lh).
#define GEMM_K_LOOP(AH, AL, BH, BL, T0, J0)                                   \
  for (int k0 = 0; k0 < NDIM; k0 += 32) {                                     \
    __syncthreads();                                                          \
    {                                                                         \
      const int row_ = tid >> 2, ch_ = (tid & 3) * 8;                         \
      gload16(AH + (size_t)(T0 + row_) * NDIM + k0 + ch_, lah + tid * 8);     \
      gload16(AH + (size_t)(T0 + 64 + row_) * NDIM + k0 + ch_,                \
              lah + 2048 + tid * 8);                                          \
      gload16(BH + (size_t)(J0 + row_) * NDIM + k0 + ch_, lbh + tid * 8);     \
      gload16(BH + (size_t)(J0 + 64 + row_) * NDIM + k0 + ch_,                \
              lbh + 2048 + tid * 8);                                          \
      gload16(AL + (size_t)(T0 + row_) * NDIM + k0 + ch_, lal + tid * 8);     \
      gload16(AL + (size_t)(T0 + 64 + row_) * NDIM + k0 + ch_,                \
              lal + 2048 + tid * 8);                                          \
      gload16(BL + (size_t)(J0 + row_) * NDIM + k0 + ch_, lbl + tid * 8);     \
      gload16(BL + (size_t)(J0 + 64 + row_) * NDIM + k0 + ch_,                \
              lbl + 2048 + tid * 8);                                          \
    }                                                                         \
    __syncthreads();                                                          \
    bf16x8 afh[4], afl[4];                                                    \
    _Pragma("unroll") for (int m = 0; m < 4; m++) {                           \
      int off = (wm * 64 + m * 16 + lr) * 32 + lg * 8;                        \
      afh[m] = ld16(lah + off);                                               \
      afl[m] = ld16(lal + off);                                               \
    }                                                                         \
    _Pragma("unroll") for (int n = 0; n < 4; n++) {                           \
      int off = (wn * 64 + n * 16 + lr) * 32 + lg * 8;                        \
      bf16x8 bfh = ld16(lbh + off);                                           \
      bf16x8 bfl = ld16(lbl + off);                                           \
      _Pragma("unroll") for (int m = 0; m < 4; m++) {                         \
        acc[m][n] = mfma16(afh[m], bfh, acc[m][n]);                           \
        acc[m][n] = mfma16(afh[m], bfl, acc[m][n]);                           \
        acc[m][n] = mfma16(afl[m], bfh, acc[m][n]);                           \
      }                                                                       \
    }                                                                         \
  }

#define GEMM_IDX_DECLS                                                        \
  const int tid = threadIdx.x;                                                \
  const int lane = tid & 63, wid = tid >> 6;                                  \
  const int wm = wid >> 1, wn = wid & 1;                                      \
  const int lr = lane & 15, lg = lane >> 4;                                   \
  u16* lah = lds;                                                             \
  u16* lbh = lds + 4096;                                                      \
  u16* lal = lds + 8192;                                                      \
  u16* lbl = lds + 12288;

// ---------------- prep: split f32 -> bf16 hi/lo ----------------
__global__ __launch_bounds__(256) void k_prep(
    const float* __restrict__ x, const float* __restrict__ wq,
    const float* __restrict__ wk, const float* __restrict__ wv,
    const float* __restrict__ wo,
    u16* __restrict__ xh, u16* __restrict__ xl,
    u16* __restrict__ wh, u16* __restrict__ wl) {
  int g = blockIdx.x * 256 + threadIdx.x;  // 4-element groups
  const float4* src;
  u16 *dh, *dl;
  int idx;
  if (g < NX / 4) {
    src = (const float4*)x; dh = xh; dl = xl; idx = g;
  } else {
    int z = (g - NX / 4) / (NWEL / 4);
    int r = (g - NX / 4) % (NWEL / 4);
    src = (const float4*)(z == 0 ? wq : z == 1 ? wk : z == 2 ? wv : wo);
    dh = wh + (size_t)z * NWEL; dl = wl + (size_t)z * NWEL; idx = r;
  }
  float4 v = src[idx];
  u16 h0 = f2bf(v.x), h1 = f2bf(v.y), h2 = f2bf(v.z), h3 = f2bf(v.w);
  ushort4 hv = make_ushort4(h0, h1, h2, h3);
  ushort4 lv = make_ushort4(f2bf(v.x - bf2f(h0)), f2bf(v.y - bf2f(h1)),
                            f2bf(v.z - bf2f(h2)), f2bf(v.w - bf2f(h3)));
  ((ushort4*)dh)[idx] = hv;
  ((ushort4*)dl)[idx] = lv;
}

// ---------------- RoPE cos/sin table: [pos 0..2047][j 0..31] ------------
__global__ __launch_bounds__(256) void k_tab(float2* __restrict__ csn) {
  int idx = blockIdx.x * 256 + threadIdx.x;  // 65536 entries
  int p = idx >> 5, j = idx & 31;
  double invf = exp((double)(2 * j) * (-9.210340371976184 / 64.0));
  double ang = (double)p * invf;
  double kq = rint(ang * 0.15915494309189535);
  float a = (float)(ang - kq * 6.283185307179586);
  csn[idx] = make_float2(cosf(a), sinf(a));
}

// ---------------- QKV projection + RoPE epilogue ----------------
// z=0: Q (rope, split store), z=1: K (rope, split store), z=2: V (transposed)
__global__ __launch_bounds__(256) void k_qkv(
    const u16* __restrict__ xh, const u16* __restrict__ xl,
    const u16* __restrict__ wh, const u16* __restrict__ wl,
    const int* __restrict__ tokpos, const float2* __restrict__ csn,
    u16* __restrict__ qh, u16* __restrict__ ql,
    u16* __restrict__ kh, u16* __restrict__ kl, u16* __restrict__ vt) {
  __shared__ __align__(16) u16 lds[16384];
  const int z = blockIdx.z;
  const int t0 = blockIdx.y * 128, j0 = blockIdx.x * 128;
  const int h0 = j0 >> 6;  // first head covered by this col-tile (2 heads/tile)
  GEMM_IDX_DECLS
  const u16* Bh = wh + (size_t)z * NWEL;
  const u16* Bl = wl + (size_t)z * NWEL;
  f32x4 acc[4][4];
#pragma unroll
  for (int m = 0; m < 4; m++)
#pragma unroll
    for (int n = 0; n < 4; n++) acc[m][n] = f32x4{0.f, 0.f, 0.f, 0.f};
  GEMM_K_LOOP(xh, xl, Bh, Bl, t0, j0)

  const int b = t0 >> 11, s0 = t0 & 2047;
  if (z < 2) {
    u16* dh = (z == 0) ? qh : kh;
    u16* dl = (z == 0) ? ql : kl;
    // ---- RoPE into registers (table-driven) ----
    float rv[4][4][4];
#pragma unroll
    for (int m = 0; m < 4; m++) {
#pragma unroll
      for (int r = 0; r < 4; r++) {
        int pos = tokpos[t0 + wm * 64 + m * 16 + lg * 4 + r];
#pragma unroll
        for (int n = 0; n < 4; n++) {
          float val = acc[m][n][r];
          float nb = __shfl_xor(val, 1);
          int dk = (wn * 64 + n * 16 + lr) & 63;
          float2 cs = csn[pos * 32 + (dk >> 1)];
          rv[m][r][n] = (dk & 1) ? (nb * cs.y + val * cs.x)
                                 : (val * cs.x - nb * cs.y);
        }
      }
    }
    // ---- two staged passes (hi, then lo) through LDS, coalesced out ----
#pragma unroll
    for (int pass = 0; pass < 2; pass++) {
      __syncthreads();
#pragma unroll
      for (int m = 0; m < 4; m++)
#pragma unroll
        for (int r = 0; r < 4; r++) {
          int rloc = wm * 64 + m * 16 + lg * 4 + r;
#pragma unroll
          for (int n = 0; n < 4; n++) {
            int cloc = wn * 64 + n * 16 + lr;
            float v = rv[m][r][n];
            u16 hi = f2bf(v);
            lds[rloc * 128 + cloc] = pass == 0 ? hi : f2bf(v - bf2f(hi));
          }
        }
      __syncthreads();
      u16* dst = pass == 0 ? dh : dl;
#pragma unroll
      for (int i = 0; i < 8; i++) {
        int idx = tid + i * 256;     // 0..2047 chunks of 8 u16
        int r = idx >> 4, cc = idx & 15;
        int4 v = *(int4*)(lds + r * 128 + cc * 8);
        int h2 = cc >> 3, dk = (cc & 7) * 8;
        size_t off = ((size_t)((b * NHEAD + h0 + h2) * NSEQ + s0 + r)) * 64 + dk;
        *(int4*)(dst + off) = v;
      }
    }
  } else {
    // ---- V: transpose in LDS (swizzled), coalesced out to vt[bh][dk][s] ----
    __syncthreads();
#pragma unroll
    for (int m = 0; m < 4; m++)
#pragma unroll
      for (int r = 0; r < 4; r++) {
        int rloc = wm * 64 + m * 16 + lg * 4 + r;
#pragma unroll
        for (int n = 0; n < 4; n++) {
          int cloc = wn * 64 + n * 16 + lr;
          lds[cloc * 128 + (rloc ^ ((cloc & 15) << 3))] = f2bf(acc[m][n][r]);
        }
      }
    __syncthreads();
#pragma unroll
    for (int i = 0; i < 8; i++) {
      int idx = tid + i * 256;
      int col = idx >> 4, rc = idx & 15;
      int4 v = *(int4*)(lds + col * 128 + ((rc * 8) ^ ((col & 15) << 3)));
      int h2 = col >> 6, dk = col & 63;
      size_t off = ((size_t)((b * NHEAD + h0 + h2) * 64 + dk)) * NSEQ + s0 + rc * 8;
      *(int4*)(vt + off) = v;
    }
  }
}

// ---------------- causal flash attention ----------------
// grid (32 qblocks, 32 bh). 4 waves, each owns 16 q rows. KV tiles of 64.
__global__ __launch_bounds__(256) void k_attn(
    const u16* __restrict__ qh, const u16* __restrict__ ql,
    const u16* __restrict__ kh, const u16* __restrict__ kl,
    const u16* __restrict__ vt,
    u16* __restrict__ ah, u16* __restrict__ al) {
  __shared__ __align__(16) u16 skh[4096];
  __shared__ __align__(16) u16 skl[4096];
  __shared__ __align__(16) u16 svt[4096];
  __shared__ __align__(16) u16 sp[4096];
  const int tid = threadIdx.x, lane = tid & 63, w = tid >> 6;
  const int lr = lane & 15, lg = lane >> 4;
  const int qblk = 31 - blockIdx.x;  // heavy blocks dispatch first
  const int bh = blockIdx.y;
  const int q0 = qblk * 64;
  const size_t base = (size_t)bh * NSEQ * 64;   // q/k: [bh][s][dk]
  const size_t vbase = (size_t)bh * 64 * NSEQ;  // vt:  [bh][dk][s]

  bf16x8 qfh[2], qfl[2];
  const int qrow = q0 + w * 16 + lr;
#pragma unroll
  for (int kk = 0; kk < 2; kk++) {
    qfh[kk] = ld16(qh + base + (size_t)qrow * 64 + kk * 32 + lg * 8);
    qfl[kk] = ld16(ql + base + (size_t)qrow * 64 + kk * 32 + lg * 8);
  }
  float mrun[4], lrun[4];
  f32x4 oacc[4];
#pragma unroll
  for (int r = 0; r < 4; r++) { mrun[r] = -__builtin_inff(); lrun[r] = 0.f; }
#pragma unroll
  for (int nf = 0; nf < 4; nf++) oacc[nf] = f32x4{0.f, 0.f, 0.f, 0.f};

  for (int kt = 0; kt <= qblk; kt++) {
    __syncthreads();
#pragma unroll
    for (int t = 0; t < 2; t++) {
      int c = tid + t * 256;  // 0..511
      int row = c >> 3, co = (c & 7) * 8;
      int sco = co ^ ((row & 7) * 8);  // XOR swizzle (8-elem blocks)
      *(int4*)(skh + row * 64 + sco) =
          *(const int4*)(kh + base + (size_t)(kt * 64 + row) * 64 + co);
      *(int4*)(skl + row * 64 + sco) =
          *(const int4*)(kl + base + (size_t)(kt * 64 + row) * 64 + co);
      *(int4*)(svt + row * 64 + sco) =
          *(const int4*)(vt + vbase + (size_t)row * NSEQ + kt * 64 + co);
    }
    __syncthreads();
    // QK^T (split: hh + hl + lh)
    f32x4 sacc[4];
#pragma unroll
    for (int nf = 0; nf < 4; nf++) sacc[nf] = f32x4{0.f, 0.f, 0.f, 0.f};
#pragma unroll
    for (int nf = 0; nf < 4; nf++) {
      int krow = nf * 16 + lr;
#pragma unroll
      for (int kk = 0; kk < 2; kk++) {
        int off = krow * 64 + ((kk * 32 + lg * 8) ^ ((krow & 7) * 8));
        bf16x8 bh_ = ld16(skh + off);
        bf16x8 bl_ = ld16(skl + off);
        sacc[nf] = mfma16(qfh[kk], bh_, sacc[nf]);
        sacc[nf] = mfma16(qfh[kk], bl_, sacc[nf]);
        sacc[nf] = mfma16(qfl[kk], bh_, sacc[nf]);
      }
    }
    // scale + causal mask + online softmax
    float alpha[4];
#pragma unroll
    for (int r = 0; r < 4; r++) {
      int row = q0 + w * 16 + lg * 4 + r;
      float sv[4];
      float smax = -__builtin_inff();
#pragma unroll
      for (int nf = 0; nf < 4; nf++) {
        int colg = kt * 64 + nf * 16 + lr;
        float s = sacc[nf][r] * 0.125f;
        if (colg > row) s = -__builtin_inff();
        sv[nf] = s;
        smax = fmaxf(smax, s);
      }
#pragma unroll
      for (int o = 1; o < 16; o <<= 1) smax = fmaxf(smax, __shfl_xor(smax, o));
      float mnew = fmaxf(mrun[r], smax);
      float al_ = __expf(mrun[r] - mnew);
      float rsum = 0.f;
      int prow = w * 16 + lg * 4 + r;
#pragma unroll
      for (int nf = 0; nf < 4; nf++) {
        float p = __expf(sv[nf] - mnew);
        rsum += p;
        int pcol = nf * 16 + lr;
        sp[prow * 64 + (pcol ^ ((prow & 7) * 8))] = f2bf(p);
      }
#pragma unroll
      for (int o = 1; o < 16; o <<= 1) rsum += __shfl_xor(rsum, o);
      lrun[r] = lrun[r] * al_ + rsum;
      mrun[r] = mnew;
      alpha[r] = al_;
    }
#pragma unroll
    for (int nf = 0; nf < 4; nf++)
#pragma unroll
      for (int r = 0; r < 4; r++) oacc[nf][r] *= alpha[r];
    __syncthreads();  // order P writes before reads; all intra-wave rows
    // P * V  (plain bf16)
#pragma unroll
    for (int kk = 0; kk < 2; kk++) {
      int prow = w * 16 + lr;
      bf16x8 pa = ld16(sp + prow * 64 + ((kk * 32 + lg * 8) ^ ((prow & 7) * 8)));
#pragma unroll
      for (int nf = 0; nf < 4; nf++) {
        int vrow = nf * 16 + lr;
        bf16x8 vb = ld16(svt + vrow * 64 + ((kk * 32 + lg * 8) ^ ((vrow & 7) * 8)));
        oacc[nf] = mfma16(pa, vb, oacc[nf]);
      }
    }
  }
  // epilogue: normalize, split-store to attn-out [token][1024]
  const int b = bh >> 4, h = bh & 15;
#pragma unroll
  for (int r = 0; r < 4; r++) {
    float inv = 1.0f / lrun[r];
    int row = q0 + w * 16 + lg * 4 + r;  // s
    size_t toff = ((size_t)(b * NSEQ + row)) * NDIM + h * 64;
#pragma unroll
    for (int nf = 0; nf < 4; nf++) {
      float val = oacc[nf][r] * inv;
      u16 hi = f2bf(val);
      ah[toff + nf * 16 + lr] = hi;
      al[toff + nf * 16 + lr] = f2bf(val - bf2f(hi));
    }
  }
}

// ---------------- final projection: out = A * Wo^T (f32 store) ----------
__global__ __launch_bounds__(256) void k_out(
    const u16* __restrict__ ah, const u16* __restrict__ al,
    const u16* __restrict__ wh, const u16* __restrict__ wl,
    float* __restrict__ out) {
  __shared__ __align__(16) u16 lds[16384];
  const int t0 = blockIdx.y * 128, j0 = blockIdx.x * 128;
  GEMM_IDX_DECLS
  f32x4 acc[4][4];
#pragma unroll
  for (int m = 0; m < 4; m++)
#pragma unroll
    for (int n = 0; n < 4; n++) acc[m][n] = f32x4{0.f, 0.f, 0.f, 0.f};
  GEMM_K_LOOP(ah, al, wh, wl, t0, j0)
#pragma unroll
  for (int m = 0; m < 4; m++)
#pragma unroll
    for (int r = 0; r < 4; r++) {
      int row = t0 + wm * 64 + m * 16 + lg * 4 + r;
#pragma unroll
      for (int n = 0; n < 4; n++) {
        int col = j0 + wn * 64 + n * 16 + lr;
        out[(size_t)row * NDIM + col] = acc[m][n][r];
      }
    }
}

extern "C" void kernel_launch(void* const* d_in, const int* in_sizes, int n_in,
                              void* d_out, int out_size, void* d_ws, size_t ws_size,
                              hipStream_t stream) {
  (void)in_sizes; (void)n_in; (void)out_size; (void)ws_size;
  const float* x = (const float*)d_in[0];
  const int* tokpos = (const int*)d_in[1];
  const float* wq = (const float*)d_in[2];
  const float* wk = (const float*)d_in[3];
  const float* wv = (const float*)d_in[4];
  const float* wo = (const float*)d_in[5];
  float* out = (float*)d_out;

  u16* ws = (u16*)d_ws;
  u16* xh = ws;              // NX  (reused as attn-out hi after projections)
  u16* xl = xh + NX;         // NX  (reused as attn-out lo)
  u16* wh = xl + NX;         // 4*NWEL (q,k,v,o)
  u16* wl = wh + 4 * (size_t)NWEL;
  u16* qh = wl + 4 * (size_t)NWEL;
  u16* ql = qh + NX;
  u16* kh = ql + NX;
  u16* kl = kh + NX;
  u16* vt = kl + NX;         // ends at 75.5 MB
  float2* csn = (float2*)(vt + NX);  // +512 KB rope table

  k_prep<<<dim3(8192), dim3(256), 0, stream>>>(x, wq, wk, wv, wo, xh, xl, wh, wl);
  k_tab<<<dim3(256), dim3(256), 0, stream>>>(csn);
  k_qkv<<<dim3(8, 32, 3), dim3(256), 0, stream>>>(xh, xl, wh, wl, tokpos, csn,
                                                  qh, ql, kh, kl, vt);
  k_attn<<<dim3(32, 32), dim3(256), 0, stream>>>(qh, ql, kh, kl, vt, xh, xl);
  k_out<<<dim3(8, 32), dim3(256), 0, stream>>>(xh, xl, wh + 3 * (size_t)NWEL,
                                               wl + 3 * (size_t)NWEL, out);
}

// Round 4
// 220.900 us; speedup vs baseline: 3.5790x; 1.3299x over previous
//
#include <hip/hip_runtime.h>

typedef unsigned short u16;
typedef unsigned int u32;
typedef __attribute__((ext_vector_type(8))) __bf16 bf16x8;
typedef __attribute__((ext_vector_type(4))) float f32x4;

#define NSEQ 2048
#define NDIM 1024
#define NHEAD 16
#define NTOK 4096
#define NX   4194304   /* NTOK*NDIM */
#define NWEL 1048576   /* NDIM*NDIM */

__device__ __forceinline__ u16 f2bf(float f) {
  unsigned u = __float_as_uint(f);
  return (u16)((u + 0x7fffu + ((u >> 16) & 1u)) >> 16);
}
__device__ __forceinline__ float bf2f(u16 h) {
  return __uint_as_float(((unsigned)h) << 16);
}
__device__ __forceinline__ bf16x8 ld16(const u16* p) {
  int4 v = *reinterpret_cast<const int4*>(p);
  return __builtin_bit_cast(bf16x8, v);
}
__device__ __forceinline__ f32x4 mfma16(bf16x8 a, bf16x8 b, f32x4 c) {
  return __builtin_amdgcn_mfma_f32_16x16x32_bf16(a, b, c, 0, 0, 0);
}
// async global->LDS, 16B per lane; LDS dest = wave-uniform base + lane*16
__device__ __forceinline__ void gload16(const u16* g, u16* l) {
  __builtin_amdgcn_global_load_lds(
      (const __attribute__((address_space(1))) void*)g,
      (__attribute__((address_space(3))) void*)l, 16, 0, 0);
}

// GEMM k-loop as a macro: NO function boundary around the accumulator array
// (round-2 post-mortem: acc passed as pointer param -> SROA failure -> acc in
// scratch -> 1.7 GB of spill writes per dispatch, VGPR_Count=60).
#define GEMM_K_LOOP(AH, AL, BH, BL, T0, J0)                                   \
  for (int k0 = 0; k0 < NDIM; k0 += 32) {                                     \
    __syncthreads();                                                          \
    {                                                                         \
      const int row_ = tid >> 2, ch_ = (tid & 3) * 8;                         \
      gload16(AH + (size_t)(T0 + row_) * NDIM + k0 + ch_, lah + tid * 8);     \
      gload16(AH + (size_t)(T0 + 64 + row_) * NDIM + k0 + ch_,                \
              lah + 2048 + tid * 8);                                          \
      gload16(BH + (size_t)(J0 + row_) * NDIM + k0 + ch_, lbh + tid * 8);     \
      gload16(BH + (size_t)(J0 + 64 + row_) * NDIM + k0 + ch_,                \
              lbh + 2048 + tid * 8);                                          \
      gload16(AL + (size_t)(T0 + row_) * NDIM + k0 + ch_, lal + tid * 8);     \
      gload16(AL + (size_t)(T0 + 64 + row_) * NDIM + k0 + ch_,                \
              lal + 2048 + tid * 8);                                          \
      gload16(BL + (size_t)(J0 + row_) * NDIM + k0 + ch_, lbl + tid * 8);     \
      gload16(BL + (size_t)(J0 + 64 + row_) * NDIM + k0 + ch_,                \
              lbl + 2048 + tid * 8);                                          \
    }                                                                         \
    __syncthreads();                                                          \
    bf16x8 afh[4], afl[4];                                                    \
    _Pragma("unroll") for (int m = 0; m < 4; m++) {                           \
      int off = (wm * 64 + m * 16 + lr) * 32 + lg * 8;                        \
      afh[m] = ld16(lah + off);                                               \
      afl[m] = ld16(lal + off);                                               \
    }                                                                         \
    _Pragma("unroll") for (int n = 0; n < 4; n++) {                           \
      int off = (wn * 64 + n * 16 + lr) * 32 + lg * 8;                        \
      bf16x8 bfh = ld16(lbh + off);                                           \
      bf16x8 bfl = ld16(lbl + off);                                           \
      _Pragma("unroll") for (int m = 0; m < 4; m++) {                         \
        acc[m][n] = mfma16(afh[m], bfh, acc[m][n]);                           \
        acc[m][n] = mfma16(afh[m], bfl, acc[m][n]);                           \
        acc[m][n] = mfma16(afl[m], bfh, acc[m][n]);                           \
      }                                                                       \
    }                                                                         \
  }

#define GEMM_IDX_DECLS                                                        \
  const int tid = threadIdx.x;                                                \
  const int lane = tid & 63, wid = tid >> 6;                                  \
  const int wm = wid >> 1, wn = wid & 1;                                      \
  const int lr = lane & 15, lg = lane >> 4;                                   \
  u16* lah = lds;                                                             \
  u16* lbh = lds + 4096;                                                      \
  u16* lal = lds + 8192;                                                      \
  u16* lbl = lds + 12288;

// ---------------- prep: split f32 -> bf16 hi/lo ----------------
__global__ __launch_bounds__(256) void k_prep(
    const float* __restrict__ x, const float* __restrict__ wq,
    const float* __restrict__ wk, const float* __restrict__ wv,
    const float* __restrict__ wo,
    u16* __restrict__ xh, u16* __restrict__ xl,
    u16* __restrict__ wh, u16* __restrict__ wl) {
  int g = blockIdx.x * 256 + threadIdx.x;  // 4-element groups
  const float4* src;
  u16 *dh, *dl;
  int idx;
  if (g < NX / 4) {
    src = (const float4*)x; dh = xh; dl = xl; idx = g;
  } else {
    int z = (g - NX / 4) / (NWEL / 4);
    int r = (g - NX / 4) % (NWEL / 4);
    src = (const float4*)(z == 0 ? wq : z == 1 ? wk : z == 2 ? wv : wo);
    dh = wh + (size_t)z * NWEL; dl = wl + (size_t)z * NWEL; idx = r;
  }
  float4 v = src[idx];
  u16 h0 = f2bf(v.x), h1 = f2bf(v.y), h2 = f2bf(v.z), h3 = f2bf(v.w);
  ushort4 hv = make_ushort4(h0, h1, h2, h3);
  ushort4 lv = make_ushort4(f2bf(v.x - bf2f(h0)), f2bf(v.y - bf2f(h1)),
                            f2bf(v.z - bf2f(h2)), f2bf(v.w - bf2f(h3)));
  ((ushort4*)dh)[idx] = hv;
  ((ushort4*)dl)[idx] = lv;
}

// ---------------- RoPE cos/sin table: [pos 0..2047][j 0..31] ------------
__global__ __launch_bounds__(256) void k_tab(float2* __restrict__ csn) {
  int idx = blockIdx.x * 256 + threadIdx.x;  // 65536 entries
  int p = idx >> 5, j = idx & 31;
  double invf = exp((double)(2 * j) * (-9.210340371976184 / 64.0));
  double ang = (double)p * invf;
  double kq = rint(ang * 0.15915494309189535);
  float a = (float)(ang - kq * 6.283185307179586);
  csn[idx] = make_float2(cosf(a), sinf(a));
}

// ---------------- QKV projection + RoPE epilogue ----------------
__global__ __launch_bounds__(256) void k_qkv(
    const u16* __restrict__ xh, const u16* __restrict__ xl,
    const u16* __restrict__ wh, const u16* __restrict__ wl,
    const int* __restrict__ tokpos, const float2* __restrict__ csn,
    u16* __restrict__ qh, u16* __restrict__ ql,
    u16* __restrict__ kh, u16* __restrict__ kl, u16* __restrict__ vt) {
  __shared__ __align__(16) u16 lds[16384];
  const int z = blockIdx.z;
  const int t0 = blockIdx.y * 128, j0 = blockIdx.x * 128;
  const int h0 = j0 >> 6;  // first head covered by this col-tile (2 heads/tile)
  GEMM_IDX_DECLS
  const u16* Bh = wh + (size_t)z * NWEL;
  const u16* Bl = wl + (size_t)z * NWEL;
  f32x4 acc[4][4];
#pragma unroll
  for (int m = 0; m < 4; m++)
#pragma unroll
    for (int n = 0; n < 4; n++) acc[m][n] = f32x4{0.f, 0.f, 0.f, 0.f};
  GEMM_K_LOOP(xh, xl, Bh, Bl, t0, j0)

  const int b = t0 >> 11, s0 = t0 & 2047;
  if (z < 2) {
    u16* dh = (z == 0) ? qh : kh;
    u16* dl = (z == 0) ? ql : kl;
    float rv[4][4][4];
#pragma unroll
    for (int m = 0; m < 4; m++) {
#pragma unroll
      for (int r = 0; r < 4; r++) {
        int pos = tokpos[t0 + wm * 64 + m * 16 + lg * 4 + r];
#pragma unroll
        for (int n = 0; n < 4; n++) {
          float val = acc[m][n][r];
          float nb = __shfl_xor(val, 1);
          int dk = (wn * 64 + n * 16 + lr) & 63;
          float2 cs = csn[pos * 32 + (dk >> 1)];
          rv[m][r][n] = (dk & 1) ? (nb * cs.y + val * cs.x)
                                 : (val * cs.x - nb * cs.y);
        }
      }
    }
#pragma unroll
    for (int pass = 0; pass < 2; pass++) {
      __syncthreads();
#pragma unroll
      for (int m = 0; m < 4; m++)
#pragma unroll
        for (int r = 0; r < 4; r++) {
          int rloc = wm * 64 + m * 16 + lg * 4 + r;
#pragma unroll
          for (int n = 0; n < 4; n++) {
            int cloc = wn * 64 + n * 16 + lr;
            float v = rv[m][r][n];
            u16 hi = f2bf(v);
            lds[rloc * 128 + cloc] = pass == 0 ? hi : f2bf(v - bf2f(hi));
          }
        }
      __syncthreads();
      u16* dst = pass == 0 ? dh : dl;
#pragma unroll
      for (int i = 0; i < 8; i++) {
        int idx = tid + i * 256;     // 0..2047 chunks of 8 u16
        int r = idx >> 4, cc = idx & 15;
        int4 v = *(int4*)(lds + r * 128 + cc * 8);
        int h2 = cc >> 3, dk = (cc & 7) * 8;
        size_t off = ((size_t)((b * NHEAD + h0 + h2) * NSEQ + s0 + r)) * 64 + dk;
        *(int4*)(dst + off) = v;
      }
    }
  } else {
    // V: transpose in LDS (swizzled), coalesced out to vt[bh][dk][s]
    __syncthreads();
#pragma unroll
    for (int m = 0; m < 4; m++)
#pragma unroll
      for (int r = 0; r < 4; r++) {
        int rloc = wm * 64 + m * 16 + lg * 4 + r;
#pragma unroll
        for (int n = 0; n < 4; n++) {
          int cloc = wn * 64 + n * 16 + lr;
          lds[cloc * 128 + (rloc ^ ((cloc & 15) << 3))] = f2bf(acc[m][n][r]);
        }
      }
    __syncthreads();
#pragma unroll
    for (int i = 0; i < 8; i++) {
      int idx = tid + i * 256;
      int col = idx >> 4, rc = idx & 15;
      int4 v = *(int4*)(lds + col * 128 + ((rc * 8) ^ ((col & 15) << 3)));
      int h2 = col >> 6, dk = col & 63;
      size_t off = ((size_t)((b * NHEAD + h0 + h2) * 64 + dk)) * NSEQ + s0 + rc * 8;
      *(int4*)(vt + off) = v;
    }
  }
}

// ---------------- causal flash attention (swapped QK^T, paired q-tiles) ----
// grid (16 pairs, 32 bh), 256 thr = 4 waves, each wave owns 16 q rows.
// Block handles q-tiles (31-x) and (x): exactly 33 KV-tile iterations each.
// K/Kl/V double-buffered in LDS via global_load_lds with pre-swizzled global
// source columns (LDS dest must stay linear). Swapped QK^T: mfma(K,Q) puts a
// full q-row P-slice in each lane -> in-lane softmax + 2 shfl_xor.
#define ATT_STAGE(SEL, KT)                                                    \
  _Pragma("unroll") for (int j_ = 0; j_ < 6; j_++) {                          \
    int seg_ = w * 6 + j_;                                                    \
    int ten_ = seg_ >> 3, sub_ = seg_ & 7;                                    \
    int row_ = sub_ * 8 + (lane >> 3);                                        \
    int sc_ = ((lane & 7) * 8) ^ ((row_ & 7) * 8); /* u16 units */            \
    u16* dst_ = (ten_ == 0 ? &skh[SEL][0]                                     \
                           : ten_ == 1 ? &skl[SEL][0] : &svb[SEL][0]) +       \
                sub_ * 512;                                                   \
    const u16* src_ =                                                         \
        (ten_ == 2)                                                           \
            ? vt + vbase + (size_t)row_ * NSEQ + (KT) * 64 + sc_              \
            : (ten_ == 0 ? kh : kl) + base + (size_t)((KT) * 64 + row_) * 64 + sc_; \
    gload16(src_, dst_);                                                      \
  }

__global__ __launch_bounds__(256) void k_attn(
    const u16* __restrict__ qh, const u16* __restrict__ ql,
    const u16* __restrict__ kh, const u16* __restrict__ kl,
    const u16* __restrict__ vt,
    u16* __restrict__ ah, u16* __restrict__ al) {
  __shared__ __align__(16) u16 skh[2][4096];
  __shared__ __align__(16) u16 skl[2][4096];
  __shared__ __align__(16) u16 svb[2][4096];
  __shared__ __align__(16) u16 sp[4096];
  const int tid = threadIdx.x, lane = tid & 63, w = tid >> 6;
  const int lr = lane & 15, lg = lane >> 4;
  const int bh = blockIdx.y;
  const size_t base = (size_t)bh * NSEQ * 64;   // q/k: [bh][s][dk]
  const size_t vbase = (size_t)bh * 64 * NSEQ;  // vt:  [bh][dk][s]
  const int b = bh >> 4, h = bh & 15;
  const int qbA = 31 - blockIdx.x, qbB = blockIdx.x;

  for (int ph = 0; ph < 2; ph++) {
    const int qblk = ph ? qbB : qbA;
    const int q0 = qblk * 64;
    const int nt = qblk + 1;
    const int qrow_g = q0 + w * 16 + lr;
    // Q fragments (B-operand layout == A layout: lane row lr, k-slice lg*8)
    bf16x8 qfh[2], qfl[2];
#pragma unroll
    for (int kk = 0; kk < 2; kk++) {
      qfh[kk] = ld16(qh + base + (size_t)qrow_g * 64 + kk * 32 + lg * 8);
      qfl[kk] = ld16(ql + base + (size_t)qrow_g * 64 + kk * 32 + lg * 8);
    }
    float mrun = -__builtin_inff(), lrun = 0.f;
    f32x4 oacc[4];
#pragma unroll
    for (int nf = 0; nf < 4; nf++) oacc[nf] = f32x4{0.f, 0.f, 0.f, 0.f};

    int sel = 0;
    ATT_STAGE(0, 0)
    __syncthreads();
    for (int kt = 0; kt < nt; kt++) {
      if (kt + 1 < nt) { ATT_STAGE(sel ^ 1, kt + 1) }
      // ---- QK^T swapped: sacc[nf] holds P[k = nf*16+lg*4+r][q = lr] ----
      f32x4 sacc[4];
#pragma unroll
      for (int nf = 0; nf < 4; nf++) sacc[nf] = f32x4{0.f, 0.f, 0.f, 0.f};
#pragma unroll
      for (int nf = 0; nf < 4; nf++) {
        int krow = nf * 16 + lr;
        int swz = (krow & 7) * 8;
#pragma unroll
        for (int kk = 0; kk < 2; kk++) {
          int off = krow * 64 + ((kk * 32 + lg * 8) ^ swz);
          bf16x8 kfh = ld16(&skh[sel][0] + off);
          bf16x8 kfl = ld16(&skl[sel][0] + off);
          sacc[nf] = mfma16(kfh, qfh[kk], sacc[nf]);
          sacc[nf] = mfma16(kfl, qfh[kk], sacc[nf]);
          sacc[nf] = mfma16(kfh, qfl[kk], sacc[nf]);
        }
      }
      // ---- per-lane softmax for q-row lr ----
      float sv[4][4];
      float mm[4];
#pragma unroll
      for (int nf = 0; nf < 4; nf++) {
#pragma unroll
        for (int r = 0; r < 4; r++) sv[nf][r] = sacc[nf][r] * 0.125f;
      }
      if (kt == qblk) {  // only diagonal tile needs the causal mask
#pragma unroll
        for (int nf = 0; nf < 4; nf++)
#pragma unroll
          for (int r = 0; r < 4; r++) {
            int colg = kt * 64 + nf * 16 + lg * 4 + r;
            if (colg > qrow_g) sv[nf][r] = -__builtin_inff();
          }
      }
#pragma unroll
      for (int nf = 0; nf < 4; nf++)
        mm[nf] = fmaxf(fmaxf(sv[nf][0], sv[nf][1]), fmaxf(sv[nf][2], sv[nf][3]));
      float rmax = fmaxf(fmaxf(mm[0], mm[1]), fmaxf(mm[2], mm[3]));
      rmax = fmaxf(rmax, __shfl_xor(rmax, 16));
      rmax = fmaxf(rmax, __shfl_xor(rmax, 32));
      float mnew = fmaxf(mrun, rmax);
      float alpha = __expf(mrun - mnew);
      mrun = mnew;
      float p[4][4];
      float ss[4];
#pragma unroll
      for (int nf = 0; nf < 4; nf++) {
#pragma unroll
        for (int r = 0; r < 4; r++) p[nf][r] = __expf(sv[nf][r] - mnew);
        ss[nf] = (p[nf][0] + p[nf][1]) + (p[nf][2] + p[nf][3]);
      }
      float rsum = (ss[0] + ss[1]) + (ss[2] + ss[3]);
      rsum += __shfl_xor(rsum, 16);
      rsum += __shfl_xor(rsum, 32);
      lrun = lrun * alpha + rsum;
      // ---- pack P -> sp[q=w*16+lr][k] (swizzled), 4x ds_write_b64 ----
      {
        int prow = w * 16 + lr;
        int swz = (prow & 7) * 8;
#pragma unroll
        for (int nf = 0; nf < 4; nf++) {
          u32 w0 = (u32)f2bf(p[nf][0]) | ((u32)f2bf(p[nf][1]) << 16);
          u32 w1 = (u32)f2bf(p[nf][2]) | ((u32)f2bf(p[nf][3]) << 16);
          int col = (nf * 16 + lg * 4) ^ swz;
          *(uint2*)(&sp[prow * 64 + col]) = make_uint2(w0, w1);
        }
      }
      // ---- rescale O by alpha of its own rows (q = lg*4+r) ----
      {
        float af0 = __shfl(alpha, lg * 4 + 0);
        float af1 = __shfl(alpha, lg * 4 + 1);
        float af2 = __shfl(alpha, lg * 4 + 2);
        float af3 = __shfl(alpha, lg * 4 + 3);
#pragma unroll
        for (int nf = 0; nf < 4; nf++) {
          oacc[nf][0] *= af0; oacc[nf][1] *= af1;
          oacc[nf][2] *= af2; oacc[nf][3] *= af3;
        }
      }
      // ---- PV: A = P (own wave's rows), B = V^T rows (d = nf*16+lr) ----
      {
        int prow = w * 16 + lr;
        int pswz = (prow & 7) * 8;
#pragma unroll
        for (int kk = 0; kk < 2; kk++) {
          bf16x8 pa = ld16(&sp[prow * 64 + ((kk * 32 + lg * 8) ^ pswz)]);
#pragma unroll
          for (int nf = 0; nf < 4; nf++) {
            int vrow = nf * 16 + lr;
            bf16x8 vb = ld16(&svb[sel][0] + vrow * 64 +
                             ((kk * 32 + lg * 8) ^ ((vrow & 7) * 8)));
            oacc[nf] = mfma16(pa, vb, oacc[nf]);
          }
        }
      }
      __syncthreads();  // stage(sel^1) landed; all waves done reading sel
      sel ^= 1;
    }
    // ---- epilogue: normalize, split-store attn-out [token][1024] ----
    float inv = 1.0f / lrun;
    float iv0 = __shfl(inv, lg * 4 + 0);
    float iv1 = __shfl(inv, lg * 4 + 1);
    float iv2 = __shfl(inv, lg * 4 + 2);
    float iv3 = __shfl(inv, lg * 4 + 3);
#pragma unroll
    for (int r = 0; r < 4; r++) {
      float ivr = r == 0 ? iv0 : r == 1 ? iv1 : r == 2 ? iv2 : iv3;
      int row = q0 + w * 16 + lg * 4 + r;
      size_t toff = ((size_t)(b * NSEQ + row)) * NDIM + h * 64;
#pragma unroll
      for (int nf = 0; nf < 4; nf++) {
        float val = oacc[nf][r] * ivr;
        u16 hi = f2bf(val);
        ah[toff + nf * 16 + lr] = hi;
        al[toff + nf * 16 + lr] = f2bf(val - bf2f(hi));
      }
    }
  }
}

// ---------------- final projection: out = A * Wo^T (f32 store) ----------
__global__ __launch_bounds__(256) void k_out(
    const u16* __restrict__ ah, const u16* __restrict__ al,
    const u16* __restrict__ wh, const u16* __restrict__ wl,
    float* __restrict__ out) {
  __shared__ __align__(16) u16 lds[16384];
  const int t0 = blockIdx.y * 128, j0 = blockIdx.x * 128;
  GEMM_IDX_DECLS
  f32x4 acc[4][4];
#pragma unroll
  for (int m = 0; m < 4; m++)
#pragma unroll
    for (int n = 0; n < 4; n++) acc[m][n] = f32x4{0.f, 0.f, 0.f, 0.f};
  GEMM_K_LOOP(ah, al, wh, wl, t0, j0)
#pragma unroll
  for (int m = 0; m < 4; m++)
#pragma unroll
    for (int r = 0; r < 4; r++) {
      int row = t0 + wm * 64 + m * 16 + lg * 4 + r;
#pragma unroll
      for (int n = 0; n < 4; n++) {
        int col = j0 + wn * 64 + n * 16 + lr;
        out[(size_t)row * NDIM + col] = acc[m][n][r];
      }
    }
}

extern "C" void kernel_launch(void* const* d_in, const int* in_sizes, int n_in,
                              void* d_out, int out_size, void* d_ws, size_t ws_size,
                              hipStream_t stream) {
  (void)in_sizes; (void)n_in; (void)out_size; (void)ws_size;
  const float* x = (const float*)d_in[0];
  const int* tokpos = (const int*)d_in[1];
  const float* wq = (const float*)d_in[2];
  const float* wk = (const float*)d_in[3];
  const float* wv = (const float*)d_in[4];
  const float* wo = (const float*)d_in[5];
  float* out = (float*)d_out;

  u16* ws = (u16*)d_ws;
  u16* xh = ws;              // NX  (reused as attn-out hi after projections)
  u16* xl = xh + NX;         // NX  (reused as attn-out lo)
  u16* wh = xl + NX;         // 4*NWEL (q,k,v,o)
  u16* wl = wh + 4 * (size_t)NWEL;
  u16* qh = wl + 4 * (size_t)NWEL;
  u16* ql = qh + NX;
  u16* kh = ql + NX;
  u16* kl = kh + NX;
  u16* vt = kl + NX;         // ends at 75.5 MB
  float2* csn = (float2*)(vt + NX);  // +512 KB rope table

  k_prep<<<dim3(8192), dim3(256), 0, stream>>>(x, wq, wk, wv, wo, xh, xl, wh, wl);
  k_tab<<<dim3(256), dim3(256), 0, stream>>>(csn);
  k_qkv<<<dim3(8, 32, 3), dim3(256), 0, stream>>>(xh, xl, wh, wl, tokpos, csn,
                                                  qh, ql, kh, kl, vt);
  k_attn<<<dim3(16, 32), dim3(256), 0, stream>>>(qh, ql, kh, kl, vt, xh, xl);
  k_out<<<dim3(8, 32), dim3(256), 0, stream>>>(xh, xl, wh + 3 * (size_t)NWEL,
                                               wl + 3 * (size_t)NWEL, out);
}

// Round 5
// 179.555 us; speedup vs baseline: 4.4031x; 1.2303x over previous
//
#include <hip/hip_runtime.h>

typedef unsigned short u16;
typedef unsigned int u32;
typedef __attribute__((ext_vector_type(8))) __bf16 bf16x8;
typedef __attribute__((ext_vector_type(4))) float f32x4;

#define NSEQ 2048
#define NDIM 1024
#define NHEAD 16
#define NTOK 4096
#define NX   4194304   /* NTOK*NDIM */
#define NWEL 1048576   /* NDIM*NDIM */

__device__ __forceinline__ u16 f2bf(float f) {
  unsigned u = __float_as_uint(f);
  return (u16)((u + 0x7fffu + ((u >> 16) & 1u)) >> 16);
}
__device__ __forceinline__ float bf2f(u16 h) {
  return __uint_as_float(((unsigned)h) << 16);
}
__device__ __forceinline__ bf16x8 ld16(const u16* p) {
  int4 v = *reinterpret_cast<const int4*>(p);
  return __builtin_bit_cast(bf16x8, v);
}
__device__ __forceinline__ f32x4 mfma16(bf16x8 a, bf16x8 b, f32x4 c) {
  return __builtin_amdgcn_mfma_f32_16x16x32_bf16(a, b, c, 0, 0, 0);
}
// async global->LDS, 16B per lane; LDS dest = wave-uniform base + lane*16
__device__ __forceinline__ void gload16(const u16* g, u16* l) {
  __builtin_amdgcn_global_load_lds(
      (const __attribute__((address_space(1))) void*)g,
      (__attribute__((address_space(3))) void*)l, 16, 0, 0);
}

// GEMM k-loops stay macro-expanded: round-2 post-mortem showed a function
// boundary around the accumulator array -> SROA failure -> acc in scratch
// (1.7 GB spill traffic). Do not refactor into functions.
//
// LDS tile: [row][32] u16 rows (64B). Raw layout is an 8-way bank conflict on
// ds_read_b128 (row stride = 16 banks). Fix: store global chunk c at LDS chunk
// c ^ ((row>>1)&3). global_load_lds writes linearly, so the permutation is
// applied on the GLOBAL source chunk (both-sides involution, m173), and reads
// XOR the chunk index -> 2-way conflict (free, m136).
#define GEMM_PROLOGUE                                                         \
  const int tid = threadIdx.x;                                                \
  const int lane = tid & 63, wid = tid >> 6;                                  \
  const int wm = wid >> 1, wn = wid & 1;                                      \
  const int lr = lane & 15, lg = lane >> 4;                                   \
  const int srow_ = tid >> 2;                                                 \
  const int sch_ = ((tid & 3) ^ ((tid >> 3) & 3)) * 8;                        \
  const int rsw_ = (lg ^ ((lr >> 1) & 3)) * 8;

// ---- 3-product (split hi/lo) 128x128 GEMM, double-buffered, 1 barrier/iter.
// Buffer block (16384 u16): Ah[0,4K) Bh[4K,8K) Al[8K,12K) Bl[12K,16K).
#define STAGE3(BB, AH, AL, BH, BL, T0, J0, K0)                                \
  {                                                                           \
    u16* bb_ = (BB);                                                          \
    gload16(AH + (size_t)((T0) + srow_) * NDIM + (K0) + sch_, bb_ + tid * 8); \
    gload16(AH + (size_t)((T0) + 64 + srow_) * NDIM + (K0) + sch_,            \
            bb_ + 2048 + tid * 8);                                            \
    gload16(BH + (size_t)((J0) + srow_) * NDIM + (K0) + sch_,                 \
            bb_ + 4096 + tid * 8);                                            \
    gload16(BH + (size_t)((J0) + 64 + srow_) * NDIM + (K0) + sch_,            \
            bb_ + 6144 + tid * 8);                                            \
    gload16(AL + (size_t)((T0) + srow_) * NDIM + (K0) + sch_,                 \
            bb_ + 8192 + tid * 8);                                            \
    gload16(AL + (size_t)((T0) + 64 + srow_) * NDIM + (K0) + sch_,            \
            bb_ + 10240 + tid * 8);                                           \
    gload16(BL + (size_t)((J0) + srow_) * NDIM + (K0) + sch_,                 \
            bb_ + 12288 + tid * 8);                                           \
    gload16(BL + (size_t)((J0) + 64 + srow_) * NDIM + (K0) + sch_,            \
            bb_ + 14336 + tid * 8);                                           \
  }

#define GEMM3_LOOP(AH, AL, BH, BL, T0, J0)                                    \
  STAGE3(lds, AH, AL, BH, BL, T0, J0, 0)                                      \
  __syncthreads();                                                            \
  for (int k0 = 0; k0 < NDIM; k0 += 32) {                                     \
    u16* cb_ = lds + ((k0 >> 5) & 1) * 16384;                                 \
    if (k0 + 32 < NDIM) {                                                     \
      u16* nb_ = lds + ((((k0 >> 5) & 1) ^ 1) * 16384);                       \
      STAGE3(nb_, AH, AL, BH, BL, T0, J0, k0 + 32)                            \
    }                                                                         \
    bf16x8 afh[4], afl[4];                                                    \
    _Pragma("unroll") for (int m = 0; m < 4; m++) {                           \
      int off = (wm * 64 + m * 16 + lr) * 32 + rsw_;                          \
      afh[m] = ld16(cb_ + off);                                               \
      afl[m] = ld16(cb_ + 8192 + off);                                        \
    }                                                                         \
    _Pragma("unroll") for (int n = 0; n < 4; n++) {                           \
      int off = (wn * 64 + n * 16 + lr) * 32 + rsw_;                          \
      bf16x8 bfh = ld16(cb_ + 4096 + off);                                    \
      bf16x8 bfl = ld16(cb_ + 12288 + off);                                   \
      _Pragma("unroll") for (int m = 0; m < 4; m++) {                         \
        acc[m][n] = mfma16(afh[m], bfh, acc[m][n]);                           \
        acc[m][n] = mfma16(afh[m], bfl, acc[m][n]);                           \
        acc[m][n] = mfma16(afl[m], bfh, acc[m][n]);                           \
      }                                                                       \
    }                                                                         \
    __syncthreads();                                                          \
  }

// ---- 1-product (plain bf16) variant. Buffer block (8192 u16): A[0,4K) B[4K,8K).
#define STAGE1(BB, AH, BH, T0, J0, K0)                                        \
  {                                                                           \
    u16* bb_ = (BB);                                                          \
    gload16(AH + (size_t)((T0) + srow_) * NDIM + (K0) + sch_, bb_ + tid * 8); \
    gload16(AH + (size_t)((T0) + 64 + srow_) * NDIM + (K0) + sch_,            \
            bb_ + 2048 + tid * 8);                                            \
    gload16(BH + (size_t)((J0) + srow_) * NDIM + (K0) + sch_,                 \
            bb_ + 4096 + tid * 8);                                            \
    gload16(BH + (size_t)((J0) + 64 + srow_) * NDIM + (K0) + sch_,            \
            bb_ + 6144 + tid * 8);                                            \
  }

#define GEMM1_LOOP(AH, BH, T0, J0)                                            \
  STAGE1(lds, AH, BH, T0, J0, 0)                                              \
  __syncthreads();                                                            \
  for (int k0 = 0; k0 < NDIM; k0 += 32) {                                     \
    u16* cb_ = lds + ((k0 >> 5) & 1) * 8192;                                  \
    if (k0 + 32 < NDIM) {                                                     \
      u16* nb_ = lds + ((((k0 >> 5) & 1) ^ 1) * 8192);                        \
      STAGE1(nb_, AH, BH, T0, J0, k0 + 32)                                    \
    }                                                                         \
    bf16x8 afh[4];                                                            \
    _Pragma("unroll") for (int m = 0; m < 4; m++) {                           \
      int off = (wm * 64 + m * 16 + lr) * 32 + rsw_;                          \
      afh[m] = ld16(cb_ + off);                                               \
    }                                                                         \
    _Pragma("unroll") for (int n = 0; n < 4; n++) {                           \
      int off = (wn * 64 + n * 16 + lr) * 32 + rsw_;                          \
      bf16x8 bfh = ld16(cb_ + 4096 + off);                                    \
      _Pragma("unroll") for (int m = 0; m < 4; m++) {                         \
        acc[m][n] = mfma16(afh[m], bfh, acc[m][n]);                           \
      }                                                                       \
    }                                                                         \
    __syncthreads();                                                          \
  }

// ---------------- prep: split f32 -> bf16 hi/lo ----------------
// lo halves only needed where the 3-product GEMM reads them: x, w_q, w_k.
__global__ __launch_bounds__(256) void k_prep(
    const float* __restrict__ x, const float* __restrict__ wq,
    const float* __restrict__ wk, const float* __restrict__ wv,
    const float* __restrict__ wo,
    u16* __restrict__ xh, u16* __restrict__ xl,
    u16* __restrict__ wh, u16* __restrict__ wl) {
  int g = blockIdx.x * 256 + threadIdx.x;  // 4-element groups
  const float4* src;
  u16 *dh, *dl;
  int idx;
  bool wantlo = true;
  if (g < NX / 4) {
    src = (const float4*)x; dh = xh; dl = xl; idx = g;
  } else {
    int z = (g - NX / 4) / (NWEL / 4);
    int r = (g - NX / 4) % (NWEL / 4);
    src = (const float4*)(z == 0 ? wq : z == 1 ? wk : z == 2 ? wv : wo);
    dh = wh + (size_t)z * NWEL; dl = wl + (size_t)z * NWEL; idx = r;
    wantlo = (z < 2);
  }
  float4 v = src[idx];
  u16 h0 = f2bf(v.x), h1 = f2bf(v.y), h2 = f2bf(v.z), h3 = f2bf(v.w);
  ushort4 hv = make_ushort4(h0, h1, h2, h3);
  ((ushort4*)dh)[idx] = hv;
  if (wantlo) {
    ushort4 lv = make_ushort4(f2bf(v.x - bf2f(h0)), f2bf(v.y - bf2f(h1)),
                              f2bf(v.z - bf2f(h2)), f2bf(v.w - bf2f(h3)));
    ((ushort4*)dl)[idx] = lv;
  }
}

// ---------------- RoPE cos/sin table: [pos 0..2047][j 0..31] ------------
__global__ __launch_bounds__(256) void k_tab(float2* __restrict__ csn) {
  int idx = blockIdx.x * 256 + threadIdx.x;  // 65536 entries
  int p = idx >> 5, j = idx & 31;
  double invf = exp((double)(2 * j) * (-9.210340371976184 / 64.0));
  double ang = (double)p * invf;
  double kq = rint(ang * 0.15915494309189535);
  float a = (float)(ang - kq * 6.283185307179586);
  csn[idx] = make_float2(cosf(a), sinf(a));
}

// ---------------- Q/K projection + RoPE epilogue (split, 3-product) ------
__global__ __launch_bounds__(256) void k_qkv(
    const u16* __restrict__ xh, const u16* __restrict__ xl,
    const u16* __restrict__ wh, const u16* __restrict__ wl,
    const int* __restrict__ tokpos, const float2* __restrict__ csn,
    u16* __restrict__ qh, u16* __restrict__ ql,
    u16* __restrict__ kh, u16* __restrict__ kl) {
  __shared__ __align__(16) u16 lds[32768];
  const int z = blockIdx.z;
  const int t0 = blockIdx.y * 128, j0 = blockIdx.x * 128;
  const int h0 = j0 >> 6;  // first head covered by this col-tile (2 heads/tile)
  GEMM_PROLOGUE
  const u16* Bh = wh + (size_t)z * NWEL;
  const u16* Bl = wl + (size_t)z * NWEL;
  f32x4 acc[4][4];
#pragma unroll
  for (int m = 0; m < 4; m++)
#pragma unroll
    for (int n = 0; n < 4; n++) acc[m][n] = f32x4{0.f, 0.f, 0.f, 0.f};
  GEMM3_LOOP(xh, xl, Bh, Bl, t0, j0)

  const int b = t0 >> 11, s0 = t0 & 2047;
  u16* dh = (z == 0) ? qh : kh;
  u16* dl = (z == 0) ? ql : kl;
  // ---- RoPE into registers (table-driven) ----
  float rv[4][4][4];
#pragma unroll
  for (int m = 0; m < 4; m++) {
#pragma unroll
    for (int r = 0; r < 4; r++) {
      int pos = tokpos[t0 + wm * 64 + m * 16 + lg * 4 + r];
#pragma unroll
      for (int n = 0; n < 4; n++) {
        float val = acc[m][n][r];
        float nb = __shfl_xor(val, 1);
        int dk = (wn * 64 + n * 16 + lr) & 63;
        float2 cs = csn[pos * 32 + (dk >> 1)];
        rv[m][r][n] = (dk & 1) ? (nb * cs.y + val * cs.x)
                               : (val * cs.x - nb * cs.y);
      }
    }
  }
  // ---- two staged passes (hi, then lo) through LDS, coalesced out ----
#pragma unroll
  for (int pass = 0; pass < 2; pass++) {
    __syncthreads();
#pragma unroll
    for (int m = 0; m < 4; m++)
#pragma unroll
      for (int r = 0; r < 4; r++) {
        int rloc = wm * 64 + m * 16 + lg * 4 + r;
#pragma unroll
        for (int n = 0; n < 4; n++) {
          int cloc = wn * 64 + n * 16 + lr;
          float v = rv[m][r][n];
          u16 hi = f2bf(v);
          lds[rloc * 128 + cloc] = pass == 0 ? hi : f2bf(v - bf2f(hi));
        }
      }
    __syncthreads();
    u16* dst = pass == 0 ? dh : dl;
#pragma unroll
    for (int i = 0; i < 8; i++) {
      int idx = tid + i * 256;     // 0..2047 chunks of 8 u16
      int r = idx >> 4, cc = idx & 15;
      int4 v = *(int4*)(lds + r * 128 + cc * 8);
      int h2 = cc >> 3, dk = (cc & 7) * 8;
      size_t off = ((size_t)((b * NHEAD + h0 + h2) * NSEQ + s0 + r)) * 64 + dk;
      *(int4*)(dst + off) = v;
    }
  }
}

// ---------------- V projection (plain bf16) + transpose epilogue ---------
__global__ __launch_bounds__(256) void k_v(
    const u16* __restrict__ xh, const u16* __restrict__ wvh,
    u16* __restrict__ vt) {
  __shared__ __align__(16) u16 lds[16384];
  const int t0 = blockIdx.y * 128, j0 = blockIdx.x * 128;
  const int h0 = j0 >> 6;
  GEMM_PROLOGUE
  f32x4 acc[4][4];
#pragma unroll
  for (int m = 0; m < 4; m++)
#pragma unroll
    for (int n = 0; n < 4; n++) acc[m][n] = f32x4{0.f, 0.f, 0.f, 0.f};
  GEMM1_LOOP(xh, wvh, t0, j0)
  const int b = t0 >> 11, s0 = t0 & 2047;
  // transpose in LDS (swizzled), coalesced out to vt[bh][dk][s]
#pragma unroll
  for (int m = 0; m < 4; m++)
#pragma unroll
    for (int r = 0; r < 4; r++) {
      int rloc = wm * 64 + m * 16 + lg * 4 + r;
#pragma unroll
      for (int n = 0; n < 4; n++) {
        int cloc = wn * 64 + n * 16 + lr;
        lds[cloc * 128 + (rloc ^ ((cloc & 15) << 3))] = f2bf(acc[m][n][r]);
      }
    }
  __syncthreads();
#pragma unroll
  for (int i = 0; i < 8; i++) {
    int idx = tid + i * 256;
    int col = idx >> 4, rc = idx & 15;
    int4 v = *(int4*)(lds + col * 128 + ((rc * 8) ^ ((col & 15) << 3)));
    int h2 = col >> 6, dk = col & 63;
    size_t off = ((size_t)((b * NHEAD + h0 + h2) * 64 + dk)) * NSEQ + s0 + rc * 8;
    *(int4*)(vt + off) = v;
  }
}

// ---------------- causal flash attention (swapped QK^T, paired q-tiles) ----
// grid (16 pairs, 32 bh), 256 thr = 4 waves, each wave owns 16 q rows.
// Block handles q-tiles (31-x) and (x): exactly 33 KV-tile iterations each.
#define ATT_STAGE(SEL, KT)                                                    \
  _Pragma("unroll") for (int j_ = 0; j_ < 6; j_++) {                          \
    int seg_ = w * 6 + j_;                                                    \
    int ten_ = seg_ >> 3, sub_ = seg_ & 7;                                    \
    int row_ = sub_ * 8 + (lane >> 3);                                        \
    int sc_ = ((lane & 7) * 8) ^ ((row_ & 7) * 8); /* u16 units */            \
    u16* dst_ = (ten_ == 0 ? &skh[SEL][0]                                     \
                           : ten_ == 1 ? &skl[SEL][0] : &svb[SEL][0]) +       \
                sub_ * 512;                                                   \
    const u16* src_ =                                                         \
        (ten_ == 2)                                                           \
            ? vt + vbase + (size_t)row_ * NSEQ + (KT) * 64 + sc_              \
            : (ten_ == 0 ? kh : kl) + base + (size_t)((KT) * 64 + row_) * 64 + sc_; \
    gload16(src_, dst_);                                                      \
  }

__global__ __launch_bounds__(256) void k_attn(
    const u16* __restrict__ qh, const u16* __restrict__ ql,
    const u16* __restrict__ kh, const u16* __restrict__ kl,
    const u16* __restrict__ vt, u16* __restrict__ ah) {
  __shared__ __align__(16) u16 skh[2][4096];
  __shared__ __align__(16) u16 skl[2][4096];
  __shared__ __align__(16) u16 svb[2][4096];
  __shared__ __align__(16) u16 sp[4096];
  const int tid = threadIdx.x, lane = tid & 63, w = tid >> 6;
  const int lr = lane & 15, lg = lane >> 4;
  const int bh = blockIdx.y;
  const size_t base = (size_t)bh * NSEQ * 64;   // q/k: [bh][s][dk]
  const size_t vbase = (size_t)bh * 64 * NSEQ;  // vt:  [bh][dk][s]
  const int b = bh >> 4, h = bh & 15;
  const int qbA = 31 - blockIdx.x, qbB = blockIdx.x;

  for (int ph = 0; ph < 2; ph++) {
    const int qblk = ph ? qbB : qbA;
    const int q0 = qblk * 64;
    const int nt = qblk + 1;
    const int qrow_g = q0 + w * 16 + lr;
    bf16x8 qfh[2], qfl[2];
#pragma unroll
    for (int kk = 0; kk < 2; kk++) {
      qfh[kk] = ld16(qh + base + (size_t)qrow_g * 64 + kk * 32 + lg * 8);
      qfl[kk] = ld16(ql + base + (size_t)qrow_g * 64 + kk * 32 + lg * 8);
    }
    float mrun = -__builtin_inff(), lrun = 0.f;
    f32x4 oacc[4];
#pragma unroll
    for (int nf = 0; nf < 4; nf++) oacc[nf] = f32x4{0.f, 0.f, 0.f, 0.f};

    int sel = 0;
    ATT_STAGE(0, 0)
    __syncthreads();
    for (int kt = 0; kt < nt; kt++) {
      if (kt + 1 < nt) { ATT_STAGE(sel ^ 1, kt + 1) }
      // ---- QK^T swapped: sacc[nf] holds P[k = nf*16+lg*4+r][q = lr] ----
      f32x4 sacc[4];
#pragma unroll
      for (int nf = 0; nf < 4; nf++) sacc[nf] = f32x4{0.f, 0.f, 0.f, 0.f};
#pragma unroll
      for (int nf = 0; nf < 4; nf++) {
        int krow = nf * 16 + lr;
        int swz = (krow & 7) * 8;
#pragma unroll
        for (int kk = 0; kk < 2; kk++) {
          int off = krow * 64 + ((kk * 32 + lg * 8) ^ swz);
          bf16x8 kfh = ld16(&skh[sel][0] + off);
          bf16x8 kfl = ld16(&skl[sel][0] + off);
          sacc[nf] = mfma16(kfh, qfh[kk], sacc[nf]);
          sacc[nf] = mfma16(kfl, qfh[kk], sacc[nf]);
          sacc[nf] = mfma16(kfh, qfl[kk], sacc[nf]);
        }
      }
      // ---- per-lane softmax for q-row lr ----
      float sv[4][4];
      float mm[4];
#pragma unroll
      for (int nf = 0; nf < 4; nf++) {
#pragma unroll
        for (int r = 0; r < 4; r++) sv[nf][r] = sacc[nf][r] * 0.125f;
      }
      if (kt == qblk) {  // only diagonal tile needs the causal mask
#pragma unroll
        for (int nf = 0; nf < 4; nf++)
#pragma unroll
          for (int r = 0; r < 4; r++) {
            int colg = kt * 64 + nf * 16 + lg * 4 + r;
            if (colg > qrow_g) sv[nf][r] = -__builtin_inff();
          }
      }
#pragma unroll
      for (int nf = 0; nf < 4; nf++)
        mm[nf] = fmaxf(fmaxf(sv[nf][0], sv[nf][1]), fmaxf(sv[nf][2], sv[nf][3]));
      float rmax = fmaxf(fmaxf(mm[0], mm[1]), fmaxf(mm[2], mm[3]));
      rmax = fmaxf(rmax, __shfl_xor(rmax, 16));
      rmax = fmaxf(rmax, __shfl_xor(rmax, 32));
      float mnew = fmaxf(mrun, rmax);
      float alpha = __expf(mrun - mnew);
      mrun = mnew;
      float p[4][4];
      float ss[4];
#pragma unroll
      for (int nf = 0; nf < 4; nf++) {
#pragma unroll
        for (int r = 0; r < 4; r++) p[nf][r] = __expf(sv[nf][r] - mnew);
        ss[nf] = (p[nf][0] + p[nf][1]) + (p[nf][2] + p[nf][3]);
      }
      float rsum = (ss[0] + ss[1]) + (ss[2] + ss[3]);
      rsum += __shfl_xor(rsum, 16);
      rsum += __shfl_xor(rsum, 32);
      lrun = lrun * alpha + rsum;
      // ---- pack P -> sp[q=w*16+lr][k] (swizzled), 4x ds_write_b64 ----
      {
        int prow = w * 16 + lr;
        int swz = (prow & 7) * 8;
#pragma unroll
        for (int nf = 0; nf < 4; nf++) {
          u32 w0 = (u32)f2bf(p[nf][0]) | ((u32)f2bf(p[nf][1]) << 16);
          u32 w1 = (u32)f2bf(p[nf][2]) | ((u32)f2bf(p[nf][3]) << 16);
          int col = (nf * 16 + lg * 4) ^ swz;
          *(uint2*)(&sp[prow * 64 + col]) = make_uint2(w0, w1);
        }
      }
      // ---- rescale O by alpha of its own rows (q = lg*4+r) ----
      {
        float af0 = __shfl(alpha, lg * 4 + 0);
        float af1 = __shfl(alpha, lg * 4 + 1);
        float af2 = __shfl(alpha, lg * 4 + 2);
        float af3 = __shfl(alpha, lg * 4 + 3);
#pragma unroll
        for (int nf = 0; nf < 4; nf++) {
          oacc[nf][0] *= af0; oacc[nf][1] *= af1;
          oacc[nf][2] *= af2; oacc[nf][3] *= af3;
        }
      }
      // ---- PV: A = P (own wave's rows), B = V^T rows (d = nf*16+lr) ----
      {
        int prow = w * 16 + lr;
        int pswz = (prow & 7) * 8;
#pragma unroll
        for (int kk = 0; kk < 2; kk++) {
          bf16x8 pa = ld16(&sp[prow * 64 + ((kk * 32 + lg * 8) ^ pswz)]);
#pragma unroll
          for (int nf = 0; nf < 4; nf++) {
            int vrow = nf * 16 + lr;
            bf16x8 vb = ld16(&svb[sel][0] + vrow * 64 +
                             ((kk * 32 + lg * 8) ^ ((vrow & 7) * 8)));
            oacc[nf] = mfma16(pa, vb, oacc[nf]);
          }
        }
      }
      __syncthreads();  // stage(sel^1) landed; all waves done reading sel
      sel ^= 1;
    }
    // ---- epilogue: normalize, bf16 store attn-out [token][1024] ----
    float inv = 1.0f / lrun;
    float iv0 = __shfl(inv, lg * 4 + 0);
    float iv1 = __shfl(inv, lg * 4 + 1);
    float iv2 = __shfl(inv, lg * 4 + 2);
    float iv3 = __shfl(inv, lg * 4 + 3);
#pragma unroll
    for (int r = 0; r < 4; r++) {
      float ivr = r == 0 ? iv0 : r == 1 ? iv1 : r == 2 ? iv2 : iv3;
      int row = q0 + w * 16 + lg * 4 + r;
      size_t toff = ((size_t)(b * NSEQ + row)) * NDIM + h * 64;
#pragma unroll
      for (int nf = 0; nf < 4; nf++) {
        ah[toff + nf * 16 + lr] = f2bf(oacc[nf][r] * ivr);
      }
    }
  }
}

// ---------------- final projection: out = A * Wo^T (plain bf16, f32 store) -
__global__ __launch_bounds__(256) void k_out(
    const u16* __restrict__ ah, const u16* __restrict__ wh,
    float* __restrict__ out) {
  __shared__ __align__(16) u16 lds[16384];
  const int t0 = blockIdx.y * 128, j0 = blockIdx.x * 128;
  GEMM_PROLOGUE
  f32x4 acc[4][4];
#pragma unroll
  for (int m = 0; m < 4; m++)
#pragma unroll
    for (int n = 0; n < 4; n++) acc[m][n] = f32x4{0.f, 0.f, 0.f, 0.f};
  GEMM1_LOOP(ah, wh, t0, j0)
#pragma unroll
  for (int m = 0; m < 4; m++)
#pragma unroll
    for (int r = 0; r < 4; r++) {
      int row = t0 + wm * 64 + m * 16 + lg * 4 + r;
#pragma unroll
      for (int n = 0; n < 4; n++) {
        int col = j0 + wn * 64 + n * 16 + lr;
        out[(size_t)row * NDIM + col] = acc[m][n][r];
      }
    }
}

extern "C" void kernel_launch(void* const* d_in, const int* in_sizes, int n_in,
                              void* d_out, int out_size, void* d_ws, size_t ws_size,
                              hipStream_t stream) {
  (void)in_sizes; (void)n_in; (void)out_size; (void)ws_size;
  const float* x = (const float*)d_in[0];
  const int* tokpos = (const int*)d_in[1];
  const float* wq = (const float*)d_in[2];
  const float* wk = (const float*)d_in[3];
  const float* wv = (const float*)d_in[4];
  const float* wo = (const float*)d_in[5];
  float* out = (float*)d_out;

  u16* ws = (u16*)d_ws;
  u16* xh = ws;              // NX  (reused as attn-out after projections)
  u16* xl = xh + NX;         // NX
  u16* wh = xl + NX;         // 4*NWEL (q,k,v,o)
  u16* wl = wh + 4 * (size_t)NWEL;  // lo only valid for q,k
  u16* qh = wl + 4 * (size_t)NWEL;
  u16* ql = qh + NX;
  u16* kh = ql + NX;
  u16* kl = kh + NX;
  u16* vt = kl + NX;         // ends at 75.5 MB
  float2* csn = (float2*)(vt + NX);  // +512 KB rope table

  k_prep<<<dim3(8192), dim3(256), 0, stream>>>(x, wq, wk, wv, wo, xh, xl, wh, wl);
  k_tab<<<dim3(256), dim3(256), 0, stream>>>(csn);
  k_qkv<<<dim3(8, 32, 2), dim3(256), 0, stream>>>(xh, xl, wh, wl, tokpos, csn,
                                                  qh, ql, kh, kl);
  k_v<<<dim3(8, 32), dim3(256), 0, stream>>>(xh, wh + 2 * (size_t)NWEL, vt);
  k_attn<<<dim3(16, 32), dim3(256), 0, stream>>>(qh, ql, kh, kl, vt, xh);
  k_out<<<dim3(8, 32), dim3(256), 0, stream>>>(xh, wh + 3 * (size_t)NWEL, out);
}